// Round 1
// baseline (1398.851 us; speedup 1.0000x reference)
//
#include <hip/hip_runtime.h>
#include <math.h>

// Round 0: correct f32 baseline.
//   LN -> 6x projection GEMM (batched via grid.z) -> fused attention (2-phase,
//   raw-score round trip through the w output region) -> Wo GEMM.
// All f32 vector math; no MFMA yet (precision headroom to be established first).

#define DMODEL 1024
#define NH 16
#define HD 64
#define SKV 1088
#define SCALE 0.125f

// ---------------------------------------------------------------- LayerNorm
__global__ __launch_bounds__(256) void ln_kernel(const float* __restrict__ x,
                                                 const float* __restrict__ g,
                                                 const float* __restrict__ bta,
                                                 float* __restrict__ y) {
  int row = blockIdx.x;
  const float4* xr = (const float4*)(x + (size_t)row * DMODEL);
  float4 v = xr[threadIdx.x];
  float s = v.x + v.y + v.z + v.w;
  float s2 = v.x * v.x + v.y * v.y + v.z * v.z + v.w * v.w;
  for (int off = 32; off > 0; off >>= 1) {
    s += __shfl_down(s, off, 64);
    s2 += __shfl_down(s2, off, 64);
  }
  __shared__ float ls[4], ls2[4];
  int wid = threadIdx.x >> 6;
  if ((threadIdx.x & 63) == 0) { ls[wid] = s; ls2[wid] = s2; }
  __syncthreads();
  float tot = ls[0] + ls[1] + ls[2] + ls[3];
  float tot2 = ls2[0] + ls2[1] + ls2[2] + ls2[3];
  float mean = tot * (1.0f / DMODEL);
  float var = tot2 * (1.0f / DMODEL) - mean * mean;
  float rstd = rsqrtf(var + 1e-5f);
  float4 gv = ((const float4*)g)[threadIdx.x];
  float4 bv = ((const float4*)bta)[threadIdx.x];
  float4 o;
  o.x = (v.x - mean) * rstd * gv.x + bv.x;
  o.y = (v.y - mean) * rstd * gv.y + bv.y;
  o.z = (v.z - mean) * rstd * gv.z + bv.z;
  o.w = (v.w - mean) * rstd * gv.w + bv.w;
  ((float4*)(y + (size_t)row * DMODEL))[threadIdx.x] = o;
}

// ---------------------------------------------------------------- GEMM (NT)
// C[rowOut(r), n] = (sum_k A[r,k] * W[n,k] + bias[n]) * scale
// rowOut(r) = (r / Sin) * Sout + seq_off + (r % Sin)   (concat-seq remap)
struct GemmJob {
  const float* A;
  const float* W;
  const float* bias;
  float* C;
  int M, Sin, Sout, seq_off;
  float scale;
};
struct GemmJobs { GemmJob j[6]; };

__global__ __launch_bounds__(256) void gemm_nt(GemmJobs jobs) {
  GemmJob jb = jobs.j[blockIdx.z];
  int m0 = blockIdx.y * 128;
  if (m0 >= jb.M) return;
  int n0 = blockIdx.x * 128;

  __shared__ float As[16][132];  // [k][m], stride 132 -> 2-way bank alias (free)
  __shared__ float Ws[16][132];  // [k][n]

  int tid = threadIdx.x;
  int tx = tid & 15, ty = tid >> 4;
  float acc[8][8];
#pragma unroll
  for (int i = 0; i < 8; i++)
#pragma unroll
    for (int j = 0; j < 8; j++) acc[i][j] = 0.f;

  for (int k0 = 0; k0 < DMODEL; k0 += 16) {
#pragma unroll
    for (int r = 0; r < 2; ++r) {
      int f = tid + r * 256;
      int m = f >> 2;
      int kq = (f & 3) << 2;
      float4 a = *(const float4*)(jb.A + (size_t)(m0 + m) * DMODEL + k0 + kq);
      As[kq + 0][m] = a.x; As[kq + 1][m] = a.y; As[kq + 2][m] = a.z; As[kq + 3][m] = a.w;
      float4 w = *(const float4*)(jb.W + (size_t)(n0 + m) * DMODEL + k0 + kq);
      Ws[kq + 0][m] = w.x; Ws[kq + 1][m] = w.y; Ws[kq + 2][m] = w.z; Ws[kq + 3][m] = w.w;
    }
    __syncthreads();
#pragma unroll
    for (int kk = 0; kk < 16; ++kk) {
      float4 a0 = *(const float4*)&As[kk][ty * 8];
      float4 a1 = *(const float4*)&As[kk][ty * 8 + 4];
      float4 w0 = *(const float4*)&Ws[kk][tx * 8];
      float4 w1 = *(const float4*)&Ws[kk][tx * 8 + 4];
      float av[8] = {a0.x, a0.y, a0.z, a0.w, a1.x, a1.y, a1.z, a1.w};
      float wv[8] = {w0.x, w0.y, w0.z, w0.w, w1.x, w1.y, w1.z, w1.w};
#pragma unroll
      for (int i = 0; i < 8; i++)
#pragma unroll
        for (int j = 0; j < 8; j++) acc[i][j] = fmaf(av[i], wv[j], acc[i][j]);
    }
    __syncthreads();
  }

  float bias0[8];
#pragma unroll
  for (int j = 0; j < 8; j++) bias0[j] = jb.bias[n0 + tx * 8 + j];
#pragma unroll
  for (int i = 0; i < 8; i++) {
    int r = m0 + ty * 8 + i;
    int rowOut = (r / jb.Sin) * jb.Sout + jb.seq_off + (r % jb.Sin);
    float* crow = jb.C + (size_t)rowOut * DMODEL + n0 + tx * 8;
    float4 o0, o1;
    o0.x = (acc[i][0] + bias0[0]) * jb.scale;
    o0.y = (acc[i][1] + bias0[1]) * jb.scale;
    o0.z = (acc[i][2] + bias0[2]) * jb.scale;
    o0.w = (acc[i][3] + bias0[3]) * jb.scale;
    o1.x = (acc[i][4] + bias0[4]) * jb.scale;
    o1.y = (acc[i][5] + bias0[5]) * jb.scale;
    o1.z = (acc[i][6] + bias0[6]) * jb.scale;
    o1.w = (acc[i][7] + bias0[7]) * jb.scale;
    ((float4*)crow)[0] = o0;
    ((float4*)crow)[1] = o1;
  }
}

// ---------------------------------------------------------------- Attention
// Block: one (modality, b, h, 32-q tile). Phase 1: scores -> raw to global w,
// online (m,l). Phase 2: re-read raw scores, write normalized w, o = w @ V.
__global__ __launch_bounds__(256) void attn_kernel(
    const float* __restrict__ Qtext, const float* __restrict__ Qimage,
    const float* __restrict__ Kc, const float* __restrict__ Vc,
    float* __restrict__ Wt, float* __restrict__ Wi,
    float* __restrict__ Ot, float* __restrict__ Oi) {
  const int mod = blockIdx.z;
  const int Sq = mod ? 576 : 512;
  const int q0 = blockIdx.x * 32;
  if (q0 >= Sq) return;
  const int bh = blockIdx.y;
  const int b = bh >> 4, h = bh & 15;
  const float* Q = mod ? Qimage : Qtext;
  float* Wout = mod ? Wi : Wt;
  float* O = mod ? Oi : Ot;

  __shared__ float Qs[32][68];
  __shared__ float KVs[64][68];
  __shared__ float Wsh[32][68];
  __shared__ float red[32][17];
  __shared__ float mrow[32], lrow[32], rlrow[32];

  const int tid = threadIdx.x;
  const int qg = tid & 15;   // -> q pair
  const int kg = tid >> 4;   // -> 4-k group (phase 1) / 4-d group (phase 2)
  const int q2 = qg * 2;

#pragma unroll
  for (int r = 0; r < 2; ++r) {
    int f = tid + r * 256;
    int q = f >> 4;
    int dc = (f & 15) << 2;
    float4 v = *(const float4*)(Q + (size_t)(b * Sq + q0 + q) * DMODEL + h * HD + dc);
    *(float4*)&Qs[q][dc] = v;
  }
  if (tid < 32) { mrow[tid] = -1e30f; lrow[tid] = 0.f; }
  __syncthreads();

  const size_t wbase = ((size_t)bh * Sq + q0) * SKV;

  // ---- Phase 1: scores + online softmax stats ----
  for (int kt = 0; kt < 17; ++kt) {
    int k0 = kt * 64;
#pragma unroll
    for (int r = 0; r < 4; ++r) {
      int f = tid + r * 256;
      int kr = f >> 4;
      int dc = (f & 15) << 2;
      *(float4*)&KVs[kr][dc] =
          *(const float4*)(Kc + (size_t)(b * SKV + k0 + kr) * DMODEL + h * HD + dc);
    }
    __syncthreads();

    float acc[2][4];
#pragma unroll
    for (int a = 0; a < 2; a++)
#pragma unroll
      for (int j = 0; j < 4; j++) acc[a][j] = 0.f;

    for (int d = 0; d < 64; d += 4) {
      float4 qa = *(const float4*)&Qs[q2][d];
      float4 qb = *(const float4*)&Qs[q2 + 1][d];
      float qa_[4] = {qa.x, qa.y, qa.z, qa.w};
      float qb_[4] = {qb.x, qb.y, qb.z, qb.w};
#pragma unroll
      for (int j = 0; j < 4; ++j) {
        float4 kv = *(const float4*)&KVs[kg * 4 + j][d];
        float kv_[4] = {kv.x, kv.y, kv.z, kv.w};
#pragma unroll
        for (int i = 0; i < 4; ++i) {
          acc[0][j] = fmaf(qa_[i], kv_[i], acc[0][j]);
          acc[1][j] = fmaf(qb_[i], kv_[i], acc[1][j]);
        }
      }
    }
    // raw scores to global (fixed up in phase 2)
#pragma unroll
    for (int a = 0; a < 2; ++a) {
      float4 o;
      o.x = acc[a][0]; o.y = acc[a][1]; o.z = acc[a][2]; o.w = acc[a][3];
      *(float4*)(Wout + wbase + (size_t)(q2 + a) * SKV + k0 + kg * 4) = o;
    }
    // running max
    red[q2][kg] = fmaxf(fmaxf(acc[0][0], acc[0][1]), fmaxf(acc[0][2], acc[0][3]));
    red[q2 + 1][kg] = fmaxf(fmaxf(acc[1][0], acc[1][1]), fmaxf(acc[1][2], acc[1][3]));
    __syncthreads();
    if (tid < 32) {
      float mo = mrow[tid];
      float mx = mo;
#pragma unroll
      for (int g2 = 0; g2 < 16; ++g2) mx = fmaxf(mx, red[tid][g2]);
      mrow[tid] = mx;
      lrow[tid] *= __expf(mo - mx);
    }
    __syncthreads();
    float mq0 = mrow[q2], mq1 = mrow[q2 + 1];
    red[q2][kg] = __expf(acc[0][0] - mq0) + __expf(acc[0][1] - mq0) +
                  __expf(acc[0][2] - mq0) + __expf(acc[0][3] - mq0);
    red[q2 + 1][kg] = __expf(acc[1][0] - mq1) + __expf(acc[1][1] - mq1) +
                      __expf(acc[1][2] - mq1) + __expf(acc[1][3] - mq1);
    __syncthreads();
    if (tid < 32) {
      float l = lrow[tid];
#pragma unroll
      for (int g2 = 0; g2 < 16; ++g2) l += red[tid][g2];
      lrow[tid] = l;
    }
    __syncthreads();
  }
  if (tid < 32) rlrow[tid] = 1.0f / lrow[tid];
  __syncthreads();

  // ---- Phase 2: normalize w, accumulate o ----
  const int d4 = kg * 4;
  float oacc[2][4];
#pragma unroll
  for (int a = 0; a < 2; a++)
#pragma unroll
    for (int j = 0; j < 4; j++) oacc[a][j] = 0.f;
  float mq[2] = {mrow[q2], mrow[q2 + 1]};
  float rl[2] = {rlrow[q2], rlrow[q2 + 1]};

  for (int kt = 0; kt < 17; ++kt) {
    int k0 = kt * 64;
#pragma unroll
    for (int r = 0; r < 4; ++r) {
      int f = tid + r * 256;
      int kr = f >> 4;
      int dc = (f & 15) << 2;
      *(float4*)&KVs[kr][dc] =
          *(const float4*)(Vc + (size_t)(b * SKV + k0 + kr) * DMODEL + h * HD + dc);
    }
#pragma unroll
    for (int a = 0; a < 2; ++a) {
      float* wp = Wout + wbase + (size_t)(q2 + a) * SKV + k0 + kg * 4;
      float4 sRaw = *(const float4*)wp;
      float4 e;
      e.x = __expf(sRaw.x - mq[a]) * rl[a];
      e.y = __expf(sRaw.y - mq[a]) * rl[a];
      e.z = __expf(sRaw.z - mq[a]) * rl[a];
      e.w = __expf(sRaw.w - mq[a]) * rl[a];
      *(float4*)wp = e;
      *(float4*)&Wsh[q2 + a][kg * 4] = e;
    }
    __syncthreads();
    for (int kk = 0; kk < 64; kk += 4) {
      float4 w0 = *(const float4*)&Wsh[q2][kk];
      float4 w1 = *(const float4*)&Wsh[q2 + 1][kk];
      float wv0[4] = {w0.x, w0.y, w0.z, w0.w};
      float wv1[4] = {w1.x, w1.y, w1.z, w1.w};
#pragma unroll
      for (int i = 0; i < 4; ++i) {
        float4 v = *(const float4*)&KVs[kk + i][d4];
        float vv[4] = {v.x, v.y, v.z, v.w};
#pragma unroll
        for (int j = 0; j < 4; ++j) {
          oacc[0][j] = fmaf(wv0[i], vv[j], oacc[0][j]);
          oacc[1][j] = fmaf(wv1[i], vv[j], oacc[1][j]);
        }
      }
    }
    __syncthreads();
  }
#pragma unroll
  for (int a = 0; a < 2; ++a) {
    float4 o;
    o.x = oacc[a][0]; o.y = oacc[a][1]; o.z = oacc[a][2]; o.w = oacc[a][3];
    *(float4*)(O + (size_t)(b * Sq + q0 + q2 + a) * DMODEL + h * HD + d4) = o;
  }
}

// ---------------------------------------------------------------- launch
extern "C" void kernel_launch(void* const* d_in, const int* in_sizes, int n_in,
                              void* d_out, int out_size, void* d_ws, size_t ws_size,
                              hipStream_t stream) {
  const float* q_text = (const float*)d_in[0];
  const float* q_image = (const float*)d_in[1];
  const float* k_text = (const float*)d_in[2];
  const float* k_image = (const float*)d_in[3];
  const float* Wq_t = (const float*)d_in[4];
  const float* bq_t = (const float*)d_in[5];
  const float* Wk_t = (const float*)d_in[6];
  const float* bk_t = (const float*)d_in[7];
  const float* Wv_t = (const float*)d_in[8];
  const float* bv_t = (const float*)d_in[9];
  const float* Wq_i = (const float*)d_in[10];
  const float* bq_i = (const float*)d_in[11];
  const float* Wk_i = (const float*)d_in[12];
  const float* bk_i = (const float*)d_in[13];
  const float* Wv_i = (const float*)d_in[14];
  const float* bv_i = (const float*)d_in[15];
  const float* g_t = (const float*)d_in[16];
  const float* b_t = (const float*)d_in[17];
  const float* g_i = (const float*)d_in[18];
  const float* b_i = (const float*)d_in[19];
  const float* Wo = (const float*)d_in[20];
  const float* bo = (const float*)d_in[21];

  float* out = (float*)d_out;
  float* out_t = out;                 // [4,512,1024]
  float* out_i = out + 2097152;       // [4,576,1024]
  float* w_t = out + 4456448;         // [4,16,512,1088]
  float* w_i = out + 40108032;        // [4,16,576,1088]

  float* ws = (float*)d_ws;
  float* kn_t = ws;                   // 2,097,152
  float* kn_i = ws + 2097152;         // 2,359,296
  float* qn_t = ws + 4456448;         // 2,097,152
  float* qn_i = ws + 6553600;         // 2,359,296
  float* Kc = ws + 8912896;           // 4,456,448  [4,1088,1024]
  float* Vc = ws + 13369344;          // 4,456,448
  float* Qt = ws + 17825792;          // 2,097,152
  float* Qi = ws + 19922944;          // 2,359,296  (end: 22,282,240 floats)
  float* Ot = kn_t;                   // reuse (kn dead after projections)
  float* Oi = kn_i;

  ln_kernel<<<2048, 256, 0, stream>>>(k_text, g_t, b_t, kn_t);
  ln_kernel<<<2304, 256, 0, stream>>>(k_image, g_i, b_i, kn_i);
  ln_kernel<<<2048, 256, 0, stream>>>(q_text, g_t, b_t, qn_t);
  ln_kernel<<<2304, 256, 0, stream>>>(q_image, g_i, b_i, qn_i);

  GemmJobs pj;
  pj.j[0] = {kn_t, Wk_t, bk_t, Kc, 2048, 512, SKV, 0, 1.0f};
  pj.j[1] = {kn_i, Wk_i, bk_i, Kc, 2304, 576, SKV, 512, 1.0f};
  pj.j[2] = {kn_t, Wv_t, bv_t, Vc, 2048, 512, SKV, 0, 1.0f};
  pj.j[3] = {kn_i, Wv_i, bv_i, Vc, 2304, 576, SKV, 512, 1.0f};
  pj.j[4] = {qn_t, Wq_t, bq_t, Qt, 2048, 512, 512, 0, SCALE};
  pj.j[5] = {qn_i, Wq_i, bq_i, Qi, 2304, 576, 576, 0, SCALE};
  gemm_nt<<<dim3(8, 18, 6), 256, 0, stream>>>(pj);

  attn_kernel<<<dim3(18, 64, 2), 256, 0, stream>>>(Qt, Qi, Kc, Vc, w_t, w_i, Ot, Oi);

  GemmJobs oj;
  oj.j[0] = {Ot, Wo, bo, out_t, 2048, 512, 512, 0, 1.0f};
  oj.j[1] = {Oi, Wo, bo, out_i, 2304, 576, 576, 0, 1.0f};
  oj.j[2] = oj.j[0]; oj.j[3] = oj.j[0]; oj.j[4] = oj.j[0]; oj.j[5] = oj.j[0];
  gemm_nt<<<dim3(8, 18, 2), 256, 0, stream>>>(oj);
}

// Round 2
// 1017.364 us; speedup vs baseline: 1.3750x; 1.3750x over previous
//
#include <hip/hip_runtime.h>
#include <math.h>

#define DMODEL 1024
#define SKV 1088
#define SCALE 0.125f

typedef __attribute__((ext_vector_type(8))) short short8;   // 8 bf16 = 4 VGPRs
typedef __attribute__((ext_vector_type(4))) float floatx4;

__device__ __forceinline__ unsigned short bf16_rne(float f) {
  unsigned u = __float_as_uint(f);
  u = (u + 0x7FFFu + ((u >> 16) & 1u)) >> 16;
  return (unsigned short)u;
}
__device__ __forceinline__ float bf16_f32(unsigned short h) {
  return __uint_as_float(((unsigned)h) << 16);
}

// ---------------------------------------------------------------- LayerNorm -> bf16 hi/lo planes
__global__ __launch_bounds__(256) void ln_split(const float* __restrict__ x,
                                                const float* __restrict__ g,
                                                const float* __restrict__ bta,
                                                unsigned short* __restrict__ yh,
                                                unsigned short* __restrict__ yl) {
  int row = blockIdx.x;
  const float4* xr = (const float4*)(x + (size_t)row * DMODEL);
  float4 v = xr[threadIdx.x];
  float s = v.x + v.y + v.z + v.w;
  float s2 = v.x * v.x + v.y * v.y + v.z * v.z + v.w * v.w;
  for (int off = 32; off > 0; off >>= 1) {
    s += __shfl_down(s, off, 64);
    s2 += __shfl_down(s2, off, 64);
  }
  __shared__ float ls[4], ls2[4];
  int wid = threadIdx.x >> 6;
  if ((threadIdx.x & 63) == 0) { ls[wid] = s; ls2[wid] = s2; }
  __syncthreads();
  float tot = ls[0] + ls[1] + ls[2] + ls[3];
  float tot2 = ls2[0] + ls2[1] + ls2[2] + ls2[3];
  float mean = tot * (1.0f / DMODEL);
  float var = tot2 * (1.0f / DMODEL) - mean * mean;
  float rstd = rsqrtf(var + 1e-5f);
  float4 gv = ((const float4*)g)[threadIdx.x];
  float4 bv = ((const float4*)bta)[threadIdx.x];
  float4 o;
  o.x = (v.x - mean) * rstd * gv.x + bv.x;
  o.y = (v.y - mean) * rstd * gv.y + bv.y;
  o.z = (v.z - mean) * rstd * gv.z + bv.z;
  o.w = (v.w - mean) * rstd * gv.w + bv.w;
  ushort4 hv, lv;
  hv.x = bf16_rne(o.x); lv.x = bf16_rne(o.x - bf16_f32(hv.x));
  hv.y = bf16_rne(o.y); lv.y = bf16_rne(o.y - bf16_f32(hv.y));
  hv.z = bf16_rne(o.z); lv.z = bf16_rne(o.z - bf16_f32(hv.z));
  hv.w = bf16_rne(o.w); lv.w = bf16_rne(o.w - bf16_f32(hv.w));
  ((ushort4*)(yh + (size_t)row * DMODEL))[threadIdx.x] = hv;
  ((ushort4*)(yl + (size_t)row * DMODEL))[threadIdx.x] = lv;
}

// ---------------------------------------------------------------- f32 -> bf16 hi/lo split
struct ConvJob { const float* src; unsigned short* h; unsigned short* l; int n4; };
struct ConvJobs { ConvJob j[4]; };

__global__ __launch_bounds__(256) void conv_split(ConvJobs jobs) {
  ConvJob jb = jobs.j[blockIdx.y];
  int i = blockIdx.x * 256 + threadIdx.x;
  if (i >= jb.n4) return;
  float4 v = ((const float4*)jb.src)[i];
  ushort4 hv, lv;
  hv.x = bf16_rne(v.x); lv.x = bf16_rne(v.x - bf16_f32(hv.x));
  hv.y = bf16_rne(v.y); lv.y = bf16_rne(v.y - bf16_f32(hv.y));
  hv.z = bf16_rne(v.z); lv.z = bf16_rne(v.z - bf16_f32(hv.z));
  hv.w = bf16_rne(v.w); lv.w = bf16_rne(v.w - bf16_f32(hv.w));
  ((ushort4*)jb.h)[i] = hv;
  ((ushort4*)jb.l)[i] = lv;
}

// ---------------------------------------------------------------- split-bf16 MFMA GEMM (NT)
// C[rowOut(r), n] = (sum_k A[r,k]*W[n,k] + bias[n]) * scale,  A ~ Ah+Al, W ~ Wh+Wl
// 128x128 block tile, 4 waves (2x2 of 64x64), 16x16x32 bf16 MFMA, BK=32.
// LDS tiles [128 rows][4 chunks of 8 bf16], chunk slot XOR-swizzled by (row>>2)&3.
struct GemmSJob {
  const unsigned short *Ah, *Al, *Wh, *Wl;
  const float* bias;
  float* C;
  int M, Sin, Sout, seq_off;
  float scale;
};
struct GemmSJobs { GemmSJob j[4]; };

__device__ __forceinline__ int lds_slot(int m, int kc) {
  return m * 32 + ((kc ^ ((m >> 2) & 3)) << 3);  // ushort index, 16B aligned
}

__global__ __launch_bounds__(256) void gemm_split(GemmSJobs jobs) {
  GemmSJob jb = jobs.j[blockIdx.z];
  const int m0 = blockIdx.y * 128;
  if (m0 >= jb.M) return;
  const int n0 = blockIdx.x * 128;

  __shared__ __align__(16) unsigned short sAh[128 * 32];
  __shared__ __align__(16) unsigned short sAl[128 * 32];
  __shared__ __align__(16) unsigned short sWh[128 * 32];
  __shared__ __align__(16) unsigned short sWl[128 * 32];

  const int tid = threadIdx.x;
  const int lane = tid & 63;
  const int wv = tid >> 6;
  const int wm = (wv & 1) * 64;
  const int wn = (wv >> 1) * 64;

  // staging: thread covers chunk f=tid (rows 0..63) and f=tid+256 (rows 64..127)
  const int mS = tid >> 2;
  const int kcS = tid & 3;
  const int ls0 = lds_slot(mS, kcS);
  const int ls1 = lds_slot(mS + 64, kcS);
  const size_t aOff0 = (size_t)(m0 + mS) * DMODEL + kcS * 8;
  const size_t aOff1 = (size_t)(m0 + mS + 64) * DMODEL + kcS * 8;
  const size_t wOff0 = (size_t)(n0 + mS) * DMODEL + kcS * 8;
  const size_t wOff1 = (size_t)(n0 + mS + 64) * DMODEL + kcS * 8;

  // fragment read offsets (logical chunk fc, row fr within 16-tile)
  const int fr = lane & 15, fc = lane >> 4;
  int offA[4], offB[4];
#pragma unroll
  for (int t = 0; t < 4; ++t) {
    offA[t] = lds_slot(wm + t * 16 + fr, fc);
    offB[t] = lds_slot(wn + t * 16 + fr, fc);
  }

  floatx4 acc[4][4];
#pragma unroll
  for (int mt = 0; mt < 4; ++mt)
#pragma unroll
    for (int nt = 0; nt < 4; ++nt) acc[mt][nt] = (floatx4){0.f, 0.f, 0.f, 0.f};

  uint4 rAh0 = *(const uint4*)(jb.Ah + aOff0);
  uint4 rAh1 = *(const uint4*)(jb.Ah + aOff1);
  uint4 rAl0 = *(const uint4*)(jb.Al + aOff0);
  uint4 rAl1 = *(const uint4*)(jb.Al + aOff1);
  uint4 rWh0 = *(const uint4*)(jb.Wh + wOff0);
  uint4 rWh1 = *(const uint4*)(jb.Wh + wOff1);
  uint4 rWl0 = *(const uint4*)(jb.Wl + wOff0);
  uint4 rWl1 = *(const uint4*)(jb.Wl + wOff1);

  for (int k0 = 0; k0 < DMODEL; k0 += 32) {
    __syncthreads();
    *(uint4*)(sAh + ls0) = rAh0;
    *(uint4*)(sAh + ls1) = rAh1;
    *(uint4*)(sAl + ls0) = rAl0;
    *(uint4*)(sAl + ls1) = rAl1;
    *(uint4*)(sWh + ls0) = rWh0;
    *(uint4*)(sWh + ls1) = rWh1;
    *(uint4*)(sWl + ls0) = rWl0;
    *(uint4*)(sWl + ls1) = rWl1;
    __syncthreads();
    if (k0 + 32 < DMODEL) {
      const int ko = k0 + 32;
      rAh0 = *(const uint4*)(jb.Ah + aOff0 + ko);
      rAh1 = *(const uint4*)(jb.Ah + aOff1 + ko);
      rAl0 = *(const uint4*)(jb.Al + aOff0 + ko);
      rAl1 = *(const uint4*)(jb.Al + aOff1 + ko);
      rWh0 = *(const uint4*)(jb.Wh + wOff0 + ko);
      rWh1 = *(const uint4*)(jb.Wh + wOff1 + ko);
      rWl0 = *(const uint4*)(jb.Wl + wOff0 + ko);
      rWl1 = *(const uint4*)(jb.Wl + wOff1 + ko);
    }
    short8 ah[4], al[4];
#pragma unroll
    for (int t = 0; t < 4; ++t) {
      ah[t] = *(const short8*)(sAh + offA[t]);
      al[t] = *(const short8*)(sAl + offA[t]);
    }
#pragma unroll
    for (int nt = 0; nt < 4; ++nt) {
      short8 bh = *(const short8*)(sWh + offB[nt]);
      short8 bl = *(const short8*)(sWl + offB[nt]);
#pragma unroll
      for (int mt = 0; mt < 4; ++mt) {
        acc[mt][nt] = __builtin_amdgcn_mfma_f32_16x16x32_bf16(ah[mt], bh, acc[mt][nt], 0, 0, 0);
        acc[mt][nt] = __builtin_amdgcn_mfma_f32_16x16x32_bf16(ah[mt], bl, acc[mt][nt], 0, 0, 0);
        acc[mt][nt] = __builtin_amdgcn_mfma_f32_16x16x32_bf16(al[mt], bh, acc[mt][nt], 0, 0, 0);
      }
    }
  }

  float bias_v[4];
#pragma unroll
  for (int nt = 0; nt < 4; ++nt) bias_v[nt] = jb.bias[n0 + wn + nt * 16 + fr];
#pragma unroll
  for (int mt = 0; mt < 4; ++mt) {
#pragma unroll
    for (int r = 0; r < 4; ++r) {
      int rowA = m0 + wm + mt * 16 + fc * 4 + r;
      int rowOut = (rowA / jb.Sin) * jb.Sout + jb.seq_off + (rowA % jb.Sin);
      float* crow = jb.C + (size_t)rowOut * DMODEL + n0 + wn + fr;
#pragma unroll
      for (int nt = 0; nt < 4; ++nt)
        crow[nt * 16] = (acc[mt][nt][r] + bias_v[nt]) * jb.scale;
    }
  }
}

// ---------------------------------------------------------------- Attention (unchanged, f32)
__global__ __launch_bounds__(256) void attn_kernel(
    const float* __restrict__ Qtext, const float* __restrict__ Qimage,
    const float* __restrict__ Kc, const float* __restrict__ Vc,
    float* __restrict__ Wt, float* __restrict__ Wi,
    float* __restrict__ Ot, float* __restrict__ Oi) {
  const int mod = blockIdx.z;
  const int Sq = mod ? 576 : 512;
  const int q0 = blockIdx.x * 32;
  if (q0 >= Sq) return;
  const int bh = blockIdx.y;
  const int b = bh >> 4, h = bh & 15;
  const float* Q = mod ? Qimage : Qtext;
  float* Wout = mod ? Wi : Wt;
  float* O = mod ? Oi : Ot;

  __shared__ float Qs[32][68];
  __shared__ float KVs[64][68];
  __shared__ float Wsh[32][68];
  __shared__ float red[32][17];
  __shared__ float mrow[32], lrow[32], rlrow[32];

  const int tid = threadIdx.x;
  const int qg = tid & 15;
  const int kg = tid >> 4;
  const int q2 = qg * 2;

#pragma unroll
  for (int r = 0; r < 2; ++r) {
    int f = tid + r * 256;
    int q = f >> 4;
    int dc = (f & 15) << 2;
    float4 v = *(const float4*)(Q + (size_t)(b * Sq + q0 + q) * DMODEL + h * 64 + dc);
    *(float4*)&Qs[q][dc] = v;
  }
  if (tid < 32) { mrow[tid] = -1e30f; lrow[tid] = 0.f; }
  __syncthreads();

  const size_t wbase = ((size_t)bh * Sq + q0) * SKV;

  for (int kt = 0; kt < 17; ++kt) {
    int k0 = kt * 64;
#pragma unroll
    for (int r = 0; r < 4; ++r) {
      int f = tid + r * 256;
      int kr = f >> 4;
      int dc = (f & 15) << 2;
      *(float4*)&KVs[kr][dc] =
          *(const float4*)(Kc + (size_t)(b * SKV + k0 + kr) * DMODEL + h * 64 + dc);
    }
    __syncthreads();

    float acc[2][4];
#pragma unroll
    for (int a = 0; a < 2; a++)
#pragma unroll
      for (int j = 0; j < 4; j++) acc[a][j] = 0.f;

    for (int d = 0; d < 64; d += 4) {
      float4 qa = *(const float4*)&Qs[q2][d];
      float4 qb = *(const float4*)&Qs[q2 + 1][d];
      float qa_[4] = {qa.x, qa.y, qa.z, qa.w};
      float qb_[4] = {qb.x, qb.y, qb.z, qb.w};
#pragma unroll
      for (int j = 0; j < 4; ++j) {
        float4 kv = *(const float4*)&KVs[kg * 4 + j][d];
        float kv_[4] = {kv.x, kv.y, kv.z, kv.w};
#pragma unroll
        for (int i = 0; i < 4; ++i) {
          acc[0][j] = fmaf(qa_[i], kv_[i], acc[0][j]);
          acc[1][j] = fmaf(qb_[i], kv_[i], acc[1][j]);
        }
      }
    }
#pragma unroll
    for (int a = 0; a < 2; ++a) {
      float4 o;
      o.x = acc[a][0]; o.y = acc[a][1]; o.z = acc[a][2]; o.w = acc[a][3];
      *(float4*)(Wout + wbase + (size_t)(q2 + a) * SKV + k0 + kg * 4) = o;
    }
    red[q2][kg] = fmaxf(fmaxf(acc[0][0], acc[0][1]), fmaxf(acc[0][2], acc[0][3]));
    red[q2 + 1][kg] = fmaxf(fmaxf(acc[1][0], acc[1][1]), fmaxf(acc[1][2], acc[1][3]));
    __syncthreads();
    if (tid < 32) {
      float mo = mrow[tid];
      float mx = mo;
#pragma unroll
      for (int g2 = 0; g2 < 16; ++g2) mx = fmaxf(mx, red[tid][g2]);
      mrow[tid] = mx;
      lrow[tid] *= __expf(mo - mx);
    }
    __syncthreads();
    float mq0 = mrow[q2], mq1 = mrow[q2 + 1];
    red[q2][kg] = __expf(acc[0][0] - mq0) + __expf(acc[0][1] - mq0) +
                  __expf(acc[0][2] - mq0) + __expf(acc[0][3] - mq0);
    red[q2 + 1][kg] = __expf(acc[1][0] - mq1) + __expf(acc[1][1] - mq1) +
                      __expf(acc[1][2] - mq1) + __expf(acc[1][3] - mq1);
    __syncthreads();
    if (tid < 32) {
      float l = lrow[tid];
#pragma unroll
      for (int g2 = 0; g2 < 16; ++g2) l += red[tid][g2];
      lrow[tid] = l;
    }
    __syncthreads();
  }
  if (tid < 32) rlrow[tid] = 1.0f / lrow[tid];
  __syncthreads();

  const int d4 = kg * 4;
  float oacc[2][4];
#pragma unroll
  for (int a = 0; a < 2; a++)
#pragma unroll
    for (int j = 0; j < 4; j++) oacc[a][j] = 0.f;
  float mq[2] = {mrow[q2], mrow[q2 + 1]};
  float rl[2] = {rlrow[q2], rlrow[q2 + 1]};

  for (int kt = 0; kt < 17; ++kt) {
    int k0 = kt * 64;
#pragma unroll
    for (int r = 0; r < 4; ++r) {
      int f = tid + r * 256;
      int kr = f >> 4;
      int dc = (f & 15) << 2;
      *(float4*)&KVs[kr][dc] =
          *(const float4*)(Vc + (size_t)(b * SKV + k0 + kr) * DMODEL + h * 64 + dc);
    }
#pragma unroll
    for (int a = 0; a < 2; ++a) {
      float* wp = Wout + wbase + (size_t)(q2 + a) * SKV + k0 + kg * 4;
      float4 sRaw = *(const float4*)wp;
      float4 e;
      e.x = __expf(sRaw.x - mq[a]) * rl[a];
      e.y = __expf(sRaw.y - mq[a]) * rl[a];
      e.z = __expf(sRaw.z - mq[a]) * rl[a];
      e.w = __expf(sRaw.w - mq[a]) * rl[a];
      *(float4*)wp = e;
      *(float4*)&Wsh[q2 + a][kg * 4] = e;
    }
    __syncthreads();
    for (int kk = 0; kk < 64; kk += 4) {
      float4 w0 = *(const float4*)&Wsh[q2][kk];
      float4 w1 = *(const float4*)&Wsh[q2 + 1][kk];
      float wv0[4] = {w0.x, w0.y, w0.z, w0.w};
      float wv1[4] = {w1.x, w1.y, w1.z, w1.w};
#pragma unroll
      for (int i = 0; i < 4; ++i) {
        float4 v = *(const float4*)&KVs[kk + i][d4];
        float vv[4] = {v.x, v.y, v.z, v.w};
#pragma unroll
        for (int j = 0; j < 4; ++j) {
          oacc[0][j] = fmaf(wv0[i], vv[j], oacc[0][j]);
          oacc[1][j] = fmaf(wv1[i], vv[j], oacc[1][j]);
        }
      }
    }
    __syncthreads();
  }
#pragma unroll
  for (int a = 0; a < 2; ++a) {
    float4 o;
    o.x = oacc[a][0]; o.y = oacc[a][1]; o.z = oacc[a][2]; o.w = oacc[a][3];
    *(float4*)(O + (size_t)(b * Sq + q0 + q2 + a) * DMODEL + h * 64 + d4) = o;
  }
}

// ---------------------------------------------------------------- launch
extern "C" void kernel_launch(void* const* d_in, const int* in_sizes, int n_in,
                              void* d_out, int out_size, void* d_ws, size_t ws_size,
                              hipStream_t stream) {
  const float* q_text = (const float*)d_in[0];
  const float* q_image = (const float*)d_in[1];
  const float* k_text = (const float*)d_in[2];
  const float* k_image = (const float*)d_in[3];
  const float* Wq_t = (const float*)d_in[4];
  const float* bq_t = (const float*)d_in[5];
  const float* Wk_t = (const float*)d_in[6];
  const float* bk_t = (const float*)d_in[7];
  const float* Wv_t = (const float*)d_in[8];
  const float* bv_t = (const float*)d_in[9];
  const float* Wq_i = (const float*)d_in[10];
  const float* bq_i = (const float*)d_in[11];
  const float* Wk_i = (const float*)d_in[12];
  const float* bk_i = (const float*)d_in[13];
  const float* Wv_i = (const float*)d_in[14];
  const float* bv_i = (const float*)d_in[15];
  const float* g_t = (const float*)d_in[16];
  const float* b_t = (const float*)d_in[17];
  const float* g_i = (const float*)d_in[18];
  const float* b_i = (const float*)d_in[19];
  const float* Wo = (const float*)d_in[20];
  const float* bo = (const float*)d_in[21];

  float* out = (float*)d_out;
  float* out_t = out;
  float* out_i = out + 2097152;
  float* w_t = out + 4456448;
  float* w_i = out + 40108032;

  char* W = (char*)d_ws;
  float* Kc = (float*)(W + 0);              // 17,825,792 B
  float* Vc = (float*)(W + 17825792);       // 17,825,792 B
  float* Qt = (float*)(W + 35651584);       // 8,388,608 B
  float* Qi = (float*)(W + 44040192);       // 9,437,184 B
  char* R0 = W + 53477376;                  // 35,651,584 B reused region

  typedef unsigned short ush;
  // Phase A layout in R0: kn planes + Wk/Wv planes
  ush* knt_h = (ush*)(R0 + 0);
  ush* knt_l = (ush*)(R0 + 4194304);
  ush* kni_h = (ush*)(R0 + 8388608);
  ush* kni_l = (ush*)(R0 + 13107200);
  ush* wkt_h = (ush*)(R0 + 17825792);
  ush* wkt_l = (ush*)(R0 + 19922944);
  ush* wki_h = (ush*)(R0 + 22020096);
  ush* wki_l = (ush*)(R0 + 24117248);
  ush* wvt_h = (ush*)(R0 + 26214400);
  ush* wvt_l = (ush*)(R0 + 28311552);
  ush* wvi_h = (ush*)(R0 + 30408704);
  ush* wvi_l = (ush*)(R0 + 32505856);
  // Phase B layout in R0: qn planes + Wq planes
  ush* qnt_h = (ush*)(R0 + 0);
  ush* qnt_l = (ush*)(R0 + 4194304);
  ush* qni_h = (ush*)(R0 + 8388608);
  ush* qni_l = (ush*)(R0 + 13107200);
  ush* wqt_h = (ush*)(R0 + 17825792);
  ush* wqt_l = (ush*)(R0 + 19922944);
  ush* wqi_h = (ush*)(R0 + 22020096);
  ush* wqi_l = (ush*)(R0 + 24117248);
  // Phase C layout in R0: attention outputs f32 + their planes
  float* Ot = (float*)(R0 + 0);             // 8,388,608
  float* Oi = (float*)(R0 + 8388608);       // 9,437,184
  ush* ot_h = (ush*)(R0 + 17825792);
  ush* ot_l = (ush*)(R0 + 22020096);
  ush* oi_h = (ush*)(R0 + 26214400);
  ush* oi_l = (ush*)(R0 + 30932992);
  // Wo planes go in the (then-dead) Kc region
  ush* wo_h = (ush*)(W + 0);
  ush* wo_l = (ush*)(W + 2097152);

  // --- Phase A: K/V path ---
  ln_split<<<2048, 256, 0, stream>>>(k_text, g_t, b_t, knt_h, knt_l);
  ln_split<<<2304, 256, 0, stream>>>(k_image, g_i, b_i, kni_h, kni_l);

  ConvJobs cw;
  cw.j[0] = {Wk_t, wkt_h, wkt_l, 262144};
  cw.j[1] = {Wk_i, wki_h, wki_l, 262144};
  cw.j[2] = {Wv_t, wvt_h, wvt_l, 262144};
  cw.j[3] = {Wv_i, wvi_h, wvi_l, 262144};
  conv_split<<<dim3(1024, 4), 256, 0, stream>>>(cw);

  GemmSJobs kv;
  kv.j[0] = {knt_h, knt_l, wkt_h, wkt_l, bk_t, Kc, 2048, 512, SKV, 0, 1.0f};
  kv.j[1] = {kni_h, kni_l, wki_h, wki_l, bk_i, Kc, 2304, 576, SKV, 512, 1.0f};
  kv.j[2] = {knt_h, knt_l, wvt_h, wvt_l, bv_t, Vc, 2048, 512, SKV, 0, 1.0f};
  kv.j[3] = {kni_h, kni_l, wvi_h, wvi_l, bv_i, Vc, 2304, 576, SKV, 512, 1.0f};
  gemm_split<<<dim3(8, 18, 4), 256, 0, stream>>>(kv);

  // --- Phase B: Q path (reuses R0) ---
  ln_split<<<2048, 256, 0, stream>>>(q_text, g_t, b_t, qnt_h, qnt_l);
  ln_split<<<2304, 256, 0, stream>>>(q_image, g_i, b_i, qni_h, qni_l);

  ConvJobs cq;
  cq.j[0] = {Wq_t, wqt_h, wqt_l, 262144};
  cq.j[1] = {Wq_i, wqi_h, wqi_l, 262144};
  cq.j[2] = cq.j[0];
  cq.j[3] = cq.j[0];
  conv_split<<<dim3(1024, 2), 256, 0, stream>>>(cq);

  GemmSJobs qj;
  qj.j[0] = {qnt_h, qnt_l, wqt_h, wqt_l, bq_t, Qt, 2048, 512, 512, 0, SCALE};
  qj.j[1] = {qni_h, qni_l, wqi_h, wqi_l, bq_i, Qi, 2304, 576, 576, 0, SCALE};
  qj.j[2] = qj.j[0];
  qj.j[3] = qj.j[0];
  gemm_split<<<dim3(8, 18, 2), 256, 0, stream>>>(qj);

  // --- Attention (f32) ---
  attn_kernel<<<dim3(18, 64, 2), 256, 0, stream>>>(Qt, Qi, Kc, Vc, w_t, w_i, Ot, Oi);

  // --- Output projection ---
  ConvJobs co;
  co.j[0] = {Ot, ot_h, ot_l, 524288};
  co.j[1] = {Oi, oi_h, oi_l, 589824};
  co.j[2] = co.j[0];
  co.j[3] = co.j[0];
  conv_split<<<dim3(2304, 2), 256, 0, stream>>>(co);

  ConvJobs cwo;
  cwo.j[0] = {Wo, wo_h, wo_l, 262144};
  cwo.j[1] = cwo.j[0];
  cwo.j[2] = cwo.j[0];
  cwo.j[3] = cwo.j[0];
  conv_split<<<dim3(1024, 1), 256, 0, stream>>>(cwo);

  GemmSJobs oj;
  oj.j[0] = {ot_h, ot_l, wo_h, wo_l, bo, out_t, 2048, 512, 512, 0, 1.0f};
  oj.j[1] = {oi_h, oi_l, wo_h, wo_l, bo, out_i, 2304, 576, 576, 0, 1.0f};
  oj.j[2] = oj.j[0];
  oj.j[3] = oj.j[0];
  gemm_split<<<dim3(8, 18, 2), 256, 0, stream>>>(oj);
}

// Round 3
// 774.774 us; speedup vs baseline: 1.8055x; 1.3131x over previous
//
#include <hip/hip_runtime.h>
#include <math.h>

#define DMODEL 1024
#define SKV 1088
#define SCALE 0.125f

typedef __attribute__((ext_vector_type(8))) short short8;   // 8 bf16 = 4 VGPRs
typedef __attribute__((ext_vector_type(4))) float floatx4;
typedef unsigned short ush;

__device__ __forceinline__ ush bf16_rne(float f) {
  unsigned u = __float_as_uint(f);
  u = (u + 0x7FFFu + ((u >> 16) & 1u)) >> 16;
  return (ush)u;
}
__device__ __forceinline__ float bf16_f32(ush h) {
  return __uint_as_float(((unsigned)h) << 16);
}

// ---------------------------------------------------------------- LayerNorm -> bf16 hi/lo planes
__global__ __launch_bounds__(256) void ln_split(const float* __restrict__ x,
                                                const float* __restrict__ g,
                                                const float* __restrict__ bta,
                                                ush* __restrict__ yh,
                                                ush* __restrict__ yl) {
  int row = blockIdx.x;
  const float4* xr = (const float4*)(x + (size_t)row * DMODEL);
  float4 v = xr[threadIdx.x];
  float s = v.x + v.y + v.z + v.w;
  float s2 = v.x * v.x + v.y * v.y + v.z * v.z + v.w * v.w;
  for (int off = 32; off > 0; off >>= 1) {
    s += __shfl_down(s, off, 64);
    s2 += __shfl_down(s2, off, 64);
  }
  __shared__ float ls[4], ls2[4];
  int wid = threadIdx.x >> 6;
  if ((threadIdx.x & 63) == 0) { ls[wid] = s; ls2[wid] = s2; }
  __syncthreads();
  float tot = ls[0] + ls[1] + ls[2] + ls[3];
  float tot2 = ls2[0] + ls2[1] + ls2[2] + ls2[3];
  float mean = tot * (1.0f / DMODEL);
  float var = tot2 * (1.0f / DMODEL) - mean * mean;
  float rstd = rsqrtf(var + 1e-5f);
  float4 gv = ((const float4*)g)[threadIdx.x];
  float4 bv = ((const float4*)bta)[threadIdx.x];
  float4 o;
  o.x = (v.x - mean) * rstd * gv.x + bv.x;
  o.y = (v.y - mean) * rstd * gv.y + bv.y;
  o.z = (v.z - mean) * rstd * gv.z + bv.z;
  o.w = (v.w - mean) * rstd * gv.w + bv.w;
  ushort4 hv, lv;
  hv.x = bf16_rne(o.x); lv.x = bf16_rne(o.x - bf16_f32(hv.x));
  hv.y = bf16_rne(o.y); lv.y = bf16_rne(o.y - bf16_f32(hv.y));
  hv.z = bf16_rne(o.z); lv.z = bf16_rne(o.z - bf16_f32(hv.z));
  hv.w = bf16_rne(o.w); lv.w = bf16_rne(o.w - bf16_f32(hv.w));
  ((ushort4*)(yh + (size_t)row * DMODEL))[threadIdx.x] = hv;
  ((ushort4*)(yl + (size_t)row * DMODEL))[threadIdx.x] = lv;
}

// ---------------------------------------------------------------- f32 -> bf16 hi/lo split
struct ConvJob { const float* src; ush* h; ush* l; int n4; };
struct ConvJobs { ConvJob j[4]; };

__global__ __launch_bounds__(256) void conv_split(ConvJobs jobs) {
  ConvJob jb = jobs.j[blockIdx.y];
  int i = blockIdx.x * 256 + threadIdx.x;
  if (i >= jb.n4) return;
  float4 v = ((const float4*)jb.src)[i];
  ushort4 hv, lv;
  hv.x = bf16_rne(v.x); lv.x = bf16_rne(v.x - bf16_f32(hv.x));
  hv.y = bf16_rne(v.y); lv.y = bf16_rne(v.y - bf16_f32(hv.y));
  hv.z = bf16_rne(v.z); lv.z = bf16_rne(v.z - bf16_f32(hv.z));
  hv.w = bf16_rne(v.w); lv.w = bf16_rne(v.w - bf16_f32(hv.w));
  ((ushort4*)jb.h)[i] = hv;
  ((ushort4*)jb.l)[i] = lv;
}

// ---------------------------------------------------------------- split-bf16 MFMA GEMM (NT)
struct GemmSJob {
  const ush *Ah, *Al, *Wh, *Wl;
  const float* bias;
  float* C;    // f32 out (if Cb==null)
  ush* Cb;     // bf16 out (takes priority)
  int M, Sin, Sout, seq_off;
  float scale;
};
struct GemmSJobs { GemmSJob j[4]; };

__device__ __forceinline__ int lds_slot(int m, int kc) {
  return m * 32 + ((kc ^ ((m >> 2) & 3)) << 3);
}

__global__ __launch_bounds__(256) void gemm_split(GemmSJobs jobs) {
  GemmSJob jb = jobs.j[blockIdx.z];
  const int m0 = blockIdx.y * 128;
  if (m0 >= jb.M) return;
  const int n0 = blockIdx.x * 128;

  __shared__ __align__(16) ush sAh[128 * 32];
  __shared__ __align__(16) ush sAl[128 * 32];
  __shared__ __align__(16) ush sWh[128 * 32];
  __shared__ __align__(16) ush sWl[128 * 32];

  const int tid = threadIdx.x;
  const int lane = tid & 63;
  const int wv = tid >> 6;
  const int wm = (wv & 1) * 64;
  const int wn = (wv >> 1) * 64;

  const int mS = tid >> 2;
  const int kcS = tid & 3;
  const int ls0 = lds_slot(mS, kcS);
  const int ls1 = lds_slot(mS + 64, kcS);
  const size_t aOff0 = (size_t)(m0 + mS) * DMODEL + kcS * 8;
  const size_t aOff1 = (size_t)(m0 + mS + 64) * DMODEL + kcS * 8;
  const size_t wOff0 = (size_t)(n0 + mS) * DMODEL + kcS * 8;
  const size_t wOff1 = (size_t)(n0 + mS + 64) * DMODEL + kcS * 8;

  const int fr = lane & 15, fc = lane >> 4;
  int offA[4], offB[4];
#pragma unroll
  for (int t = 0; t < 4; ++t) {
    offA[t] = lds_slot(wm + t * 16 + fr, fc);
    offB[t] = lds_slot(wn + t * 16 + fr, fc);
  }

  floatx4 acc[4][4];
#pragma unroll
  for (int mt = 0; mt < 4; ++mt)
#pragma unroll
    for (int nt = 0; nt < 4; ++nt) acc[mt][nt] = (floatx4){0.f, 0.f, 0.f, 0.f};

  uint4 rAh0 = *(const uint4*)(jb.Ah + aOff0);
  uint4 rAh1 = *(const uint4*)(jb.Ah + aOff1);
  uint4 rAl0 = *(const uint4*)(jb.Al + aOff0);
  uint4 rAl1 = *(const uint4*)(jb.Al + aOff1);
  uint4 rWh0 = *(const uint4*)(jb.Wh + wOff0);
  uint4 rWh1 = *(const uint4*)(jb.Wh + wOff1);
  uint4 rWl0 = *(const uint4*)(jb.Wl + wOff0);
  uint4 rWl1 = *(const uint4*)(jb.Wl + wOff1);

  for (int k0 = 0; k0 < DMODEL; k0 += 32) {
    __syncthreads();
    *(uint4*)(sAh + ls0) = rAh0;
    *(uint4*)(sAh + ls1) = rAh1;
    *(uint4*)(sAl + ls0) = rAl0;
    *(uint4*)(sAl + ls1) = rAl1;
    *(uint4*)(sWh + ls0) = rWh0;
    *(uint4*)(sWh + ls1) = rWh1;
    *(uint4*)(sWl + ls0) = rWl0;
    *(uint4*)(sWl + ls1) = rWl1;
    __syncthreads();
    if (k0 + 32 < DMODEL) {
      const int ko = k0 + 32;
      rAh0 = *(const uint4*)(jb.Ah + aOff0 + ko);
      rAh1 = *(const uint4*)(jb.Ah + aOff1 + ko);
      rAl0 = *(const uint4*)(jb.Al + aOff0 + ko);
      rAl1 = *(const uint4*)(jb.Al + aOff1 + ko);
      rWh0 = *(const uint4*)(jb.Wh + wOff0 + ko);
      rWh1 = *(const uint4*)(jb.Wh + wOff1 + ko);
      rWl0 = *(const uint4*)(jb.Wl + wOff0 + ko);
      rWl1 = *(const uint4*)(jb.Wl + wOff1 + ko);
    }
    short8 ah[4], al[4];
#pragma unroll
    for (int t = 0; t < 4; ++t) {
      ah[t] = *(const short8*)(sAh + offA[t]);
      al[t] = *(const short8*)(sAl + offA[t]);
    }
#pragma unroll
    for (int nt = 0; nt < 4; ++nt) {
      short8 bh = *(const short8*)(sWh + offB[nt]);
      short8 bl = *(const short8*)(sWl + offB[nt]);
#pragma unroll
      for (int mt = 0; mt < 4; ++mt) {
        acc[mt][nt] = __builtin_amdgcn_mfma_f32_16x16x32_bf16(ah[mt], bh, acc[mt][nt], 0, 0, 0);
        acc[mt][nt] = __builtin_amdgcn_mfma_f32_16x16x32_bf16(ah[mt], bl, acc[mt][nt], 0, 0, 0);
        acc[mt][nt] = __builtin_amdgcn_mfma_f32_16x16x32_bf16(al[mt], bh, acc[mt][nt], 0, 0, 0);
      }
    }
  }

  float bias_v[4];
#pragma unroll
  for (int nt = 0; nt < 4; ++nt) bias_v[nt] = jb.bias[n0 + wn + nt * 16 + fr];
  if (jb.Cb) {
#pragma unroll
    for (int mt = 0; mt < 4; ++mt) {
#pragma unroll
      for (int r = 0; r < 4; ++r) {
        int rowA = m0 + wm + mt * 16 + fc * 4 + r;
        int rowOut = (rowA / jb.Sin) * jb.Sout + jb.seq_off + (rowA % jb.Sin);
        ush* crow = jb.Cb + (size_t)rowOut * DMODEL + n0 + wn + fr;
#pragma unroll
        for (int nt = 0; nt < 4; ++nt)
          crow[nt * 16] = bf16_rne((acc[mt][nt][r] + bias_v[nt]) * jb.scale);
      }
    }
  } else {
#pragma unroll
    for (int mt = 0; mt < 4; ++mt) {
#pragma unroll
      for (int r = 0; r < 4; ++r) {
        int rowA = m0 + wm + mt * 16 + fc * 4 + r;
        int rowOut = (rowA / jb.Sin) * jb.Sout + jb.seq_off + (rowA % jb.Sin);
        float* crow = jb.C + (size_t)rowOut * DMODEL + n0 + wn + fr;
#pragma unroll
        for (int nt = 0; nt < 4; ++nt)
          crow[nt * 16] = (acc[mt][nt][r] + bias_v[nt]) * jb.scale;
      }
    }
  }
}

// ---------------------------------------------------------------- V transpose: f32 [b][kv][h*64+d] -> bf16 [bh][d][kv]
__global__ __launch_bounds__(256) void vtrans(const float* __restrict__ Vc, ush* __restrict__ Vt) {
  int k0 = blockIdx.x * 64;
  int bh = blockIdx.y;
  int b = bh >> 4, h = bh & 15;
  __shared__ ush T[64][72];
  int t = threadIdx.x;
  int c4 = (t & 15) * 4;
  int r = t >> 4;
#pragma unroll
  for (int i = 0; i < 4; ++i) {
    int kr = r + i * 16;
    float4 v = *(const float4*)(Vc + (size_t)(b * SKV + k0 + kr) * DMODEL + h * 64 + c4);
    T[c4 + 0][kr] = bf16_rne(v.x);
    T[c4 + 1][kr] = bf16_rne(v.y);
    T[c4 + 2][kr] = bf16_rne(v.z);
    T[c4 + 3][kr] = bf16_rne(v.w);
  }
  __syncthreads();
#pragma unroll
  for (int i = 0; i < 4; ++i) {
    int dr = r + i * 16;
    ushort4 o;
    o.x = T[dr][c4 + 0]; o.y = T[dr][c4 + 1]; o.z = T[dr][c4 + 2]; o.w = T[dr][c4 + 3];
    *(ushort4*)(Vt + ((size_t)bh * 64 + dr) * SKV + k0 + c4) = o;
  }
}

// ---------------------------------------------------------------- MFMA flash attention
// Block = (q-tile 32, bh, mod), 4 waves: (qsub = (w&1)*16, half = w>>1).
// Sweep 1: online (m,l) per q-row via bf16 MFMA scores. Sweep 2: recompute,
// normalize, write w once, P->LDS->A-frag, O += P.V^T via MFMA.
__global__ __launch_bounds__(256) void attn_mfma(
    const ush* __restrict__ Qt, const ush* __restrict__ Qi,
    const ush* __restrict__ Kbf, const ush* __restrict__ Vtp,
    float* __restrict__ Wt, float* __restrict__ Wi,
    ush* __restrict__ OtH, ush* __restrict__ OtL,
    ush* __restrict__ OiH, ush* __restrict__ OiL) {
  const int mod = blockIdx.z;
  const int Sq = mod ? 576 : 512;
  const int q0 = blockIdx.x * 32;
  if (q0 >= Sq) return;
  const int bh = blockIdx.y;
  const int b = bh >> 4, h = bh & 15;
  const ush* Q = mod ? Qi : Qt;
  float* Wout = mod ? Wi : Wt;
  ush* OH = mod ? OiH : OtH;
  ush* OL = mod ? OiL : OtL;

  const int tid = threadIdx.x;
  const int lane = tid & 63;
  const int wv = tid >> 6;
  const int qs = (wv & 1) * 16;
  const int half = wv >> 1;
  const int fr = lane & 15;
  const int fc = lane >> 4;

  __shared__ ush Psh[32][80];   // row stride 160 B (16B-aligned reads)
  __shared__ float sm[2][2][16], sl[2][2][16];

  // persistent Q A-fragments (d 0..31, 32..63)
  const ush* qrow = Q + (size_t)(b * Sq + q0 + qs + fr) * DMODEL + h * 64 + fc * 8;
  short8 qa0 = *(const short8*)qrow;
  short8 qa1 = *(const short8*)(qrow + 32);

  const ush* Kbase = Kbf + (size_t)b * SKV * DMODEL + h * 64 + fc * 8;
  const ush* Vbase = Vtp + (size_t)bh * 64 * SKV;

  float m[4], l[4];
#pragma unroll
  for (int r = 0; r < 4; ++r) { m[r] = -1e30f; l[r] = 0.f; }

  // ---- Sweep 1: stats ----
  for (int k0 = 0; k0 < SKV; k0 += 64) {
    const ush* kr0 = Kbase + (size_t)(k0 + half * 32 + fr) * DMODEL;
    const ush* kr1 = kr0 + 16 * DMODEL;
    short8 b00 = *(const short8*)kr0;
    short8 b01 = *(const short8*)(kr0 + 32);
    short8 b10 = *(const short8*)kr1;
    short8 b11 = *(const short8*)(kr1 + 32);
    floatx4 s0 = (floatx4){0.f, 0.f, 0.f, 0.f};
    floatx4 s1 = (floatx4){0.f, 0.f, 0.f, 0.f};
    s0 = __builtin_amdgcn_mfma_f32_16x16x32_bf16(qa0, b00, s0, 0, 0, 0);
    s0 = __builtin_amdgcn_mfma_f32_16x16x32_bf16(qa1, b01, s0, 0, 0, 0);
    s1 = __builtin_amdgcn_mfma_f32_16x16x32_bf16(qa0, b10, s1, 0, 0, 0);
    s1 = __builtin_amdgcn_mfma_f32_16x16x32_bf16(qa1, b11, s1, 0, 0, 0);
#pragma unroll
    for (int r = 0; r < 4; ++r) {
      float mn = fmaxf(m[r], fmaxf(s0[r], s1[r]));
      l[r] = l[r] * __expf(m[r] - mn) + __expf(s0[r] - mn) + __expf(s1[r] - mn);
      m[r] = mn;
    }
  }
  // butterfly merge across the 16 k-columns (lanes differing in fr)
#pragma unroll
  for (int off = 1; off <= 8; off <<= 1) {
#pragma unroll
    for (int r = 0; r < 4; ++r) {
      float mo = __shfl_xor(m[r], off, 64);
      float lo = __shfl_xor(l[r], off, 64);
      float mn = fmaxf(m[r], mo);
      l[r] = l[r] * __expf(m[r] - mn) + lo * __expf(mo - mn);
      m[r] = mn;
    }
  }
  if (fr == 0) {
#pragma unroll
    for (int r = 0; r < 4; ++r) {
      sm[half][wv & 1][fc * 4 + r] = m[r];
      sl[half][wv & 1][fc * 4 + r] = l[r];
    }
  }
  __syncthreads();
  float mf[4], rl[4];
#pragma unroll
  for (int r = 0; r < 4; ++r) {
    int row = fc * 4 + r;
    float ma = sm[0][wv & 1][row], mb = sm[1][wv & 1][row];
    float la = sl[0][wv & 1][row], lb = sl[1][wv & 1][row];
    float mn = fmaxf(ma, mb);
    float lt = la * __expf(ma - mn) + lb * __expf(mb - mn);
    mf[r] = mn;
    rl[r] = 1.0f / lt;
  }

  floatx4 oacc0 = (floatx4){0.f, 0.f, 0.f, 0.f};
  floatx4 oacc1 = (floatx4){0.f, 0.f, 0.f, 0.f};

  // ---- Sweep 2: recompute, normalize, write w, PV ----
  for (int k0 = 0; k0 < SKV; k0 += 64) {
    const ush* kr0 = Kbase + (size_t)(k0 + half * 32 + fr) * DMODEL;
    const ush* kr1 = kr0 + 16 * DMODEL;
    short8 b00 = *(const short8*)kr0;
    short8 b01 = *(const short8*)(kr0 + 32);
    short8 b10 = *(const short8*)kr1;
    short8 b11 = *(const short8*)(kr1 + 32);
    floatx4 s0 = (floatx4){0.f, 0.f, 0.f, 0.f};
    floatx4 s1 = (floatx4){0.f, 0.f, 0.f, 0.f};
    s0 = __builtin_amdgcn_mfma_f32_16x16x32_bf16(qa0, b00, s0, 0, 0, 0);
    s0 = __builtin_amdgcn_mfma_f32_16x16x32_bf16(qa1, b01, s0, 0, 0, 0);
    s1 = __builtin_amdgcn_mfma_f32_16x16x32_bf16(qa0, b10, s1, 0, 0, 0);
    s1 = __builtin_amdgcn_mfma_f32_16x16x32_bf16(qa1, b11, s1, 0, 0, 0);
#pragma unroll
    for (int r = 0; r < 4; ++r) {
      float w0 = __expf(s0[r] - mf[r]) * rl[r];
      float w1 = __expf(s1[r] - mf[r]) * rl[r];
      int q = q0 + qs + fc * 4 + r;
      float* wr = Wout + ((size_t)bh * Sq + q) * SKV + k0 + half * 32 + fr;
      wr[0] = w0;
      wr[16] = w1;
      Psh[qs + fc * 4 + r][half * 32 + fr] = bf16_rne(w0);
      Psh[qs + fc * 4 + r][half * 32 + 16 + fr] = bf16_rne(w1);
    }
    __syncthreads();
    short8 pa0 = *(const short8*)&Psh[qs + fr][fc * 8];
    short8 pa1 = *(const short8*)&Psh[qs + fr][32 + fc * 8];
    const ush* v0 = Vbase + (size_t)(half * 32 + fr) * SKV + k0 + fc * 8;
    const ush* v1 = v0 + (size_t)16 * SKV;
    short8 vb00 = *(const short8*)v0;
    short8 vb01 = *(const short8*)(v0 + 32);
    short8 vb10 = *(const short8*)v1;
    short8 vb11 = *(const short8*)(v1 + 32);
    oacc0 = __builtin_amdgcn_mfma_f32_16x16x32_bf16(pa0, vb00, oacc0, 0, 0, 0);
    oacc0 = __builtin_amdgcn_mfma_f32_16x16x32_bf16(pa1, vb01, oacc0, 0, 0, 0);
    oacc1 = __builtin_amdgcn_mfma_f32_16x16x32_bf16(pa0, vb10, oacc1, 0, 0, 0);
    oacc1 = __builtin_amdgcn_mfma_f32_16x16x32_bf16(pa1, vb11, oacc1, 0, 0, 0);
    __syncthreads();
  }

  // ---- O epilogue: hi/lo bf16 planes ----
#pragma unroll
  for (int r = 0; r < 4; ++r) {
    int q = q0 + qs + fc * 4 + r;
    size_t orow = (size_t)(b * Sq + q) * DMODEL + h * 64;
    float o0 = oacc0[r], o1 = oacc1[r];
    ush h0 = bf16_rne(o0);
    ush h1 = bf16_rne(o1);
    OH[orow + half * 32 + fr] = h0;
    OL[orow + half * 32 + fr] = bf16_rne(o0 - bf16_f32(h0));
    OH[orow + half * 32 + 16 + fr] = h1;
    OL[orow + half * 32 + 16 + fr] = bf16_rne(o1 - bf16_f32(h1));
  }
}

// ---------------------------------------------------------------- launch
extern "C" void kernel_launch(void* const* d_in, const int* in_sizes, int n_in,
                              void* d_out, int out_size, void* d_ws, size_t ws_size,
                              hipStream_t stream) {
  const float* q_text = (const float*)d_in[0];
  const float* q_image = (const float*)d_in[1];
  const float* k_text = (const float*)d_in[2];
  const float* k_image = (const float*)d_in[3];
  const float* Wq_t = (const float*)d_in[4];
  const float* bq_t = (const float*)d_in[5];
  const float* Wk_t = (const float*)d_in[6];
  const float* bk_t = (const float*)d_in[7];
  const float* Wv_t = (const float*)d_in[8];
  const float* bv_t = (const float*)d_in[9];
  const float* Wq_i = (const float*)d_in[10];
  const float* bq_i = (const float*)d_in[11];
  const float* Wk_i = (const float*)d_in[12];
  const float* bk_i = (const float*)d_in[13];
  const float* Wv_i = (const float*)d_in[14];
  const float* bv_i = (const float*)d_in[15];
  const float* g_t = (const float*)d_in[16];
  const float* b_t = (const float*)d_in[17];
  const float* g_i = (const float*)d_in[18];
  const float* b_i = (const float*)d_in[19];
  const float* Wo = (const float*)d_in[20];
  const float* bo = (const float*)d_in[21];

  float* out = (float*)d_out;
  float* out_t = out;
  float* out_i = out + 2097152;
  float* w_t = out + 4456448;
  float* w_i = out + 40108032;

  char* W = (char*)d_ws;
  ush* Kbf = (ush*)(W + 0);                 // 8,912,896 B  [4][1088][1024] bf16
  ush* Qt_bf = (ush*)(W + 8912896);         // 4,194,304 B
  ush* Qi_bf = (ush*)(W + 13107200);        // 4,718,592 B
  float* Vc = (float*)(W + 17825792);       // 17,825,792 B [4][1088][1024] f32
  ush* Vt = (ush*)(W + 35651584);           // 8,912,896 B  [64bh][64d][1088k] bf16
  char* R0 = W + 44564480;                  // reused region (35.7 MB)

  // Phase A layout in R0: kn planes + Wk/Wv planes
  ush* knt_h = (ush*)(R0 + 0);
  ush* knt_l = (ush*)(R0 + 4194304);
  ush* kni_h = (ush*)(R0 + 8388608);
  ush* kni_l = (ush*)(R0 + 13107200);
  ush* wkt_h = (ush*)(R0 + 17825792);
  ush* wkt_l = (ush*)(R0 + 19922944);
  ush* wki_h = (ush*)(R0 + 22020096);
  ush* wki_l = (ush*)(R0 + 24117248);
  ush* wvt_h = (ush*)(R0 + 26214400);
  ush* wvt_l = (ush*)(R0 + 28311552);
  ush* wvi_h = (ush*)(R0 + 30408704);
  ush* wvi_l = (ush*)(R0 + 32505856);
  // Phase B layout in R0: qn planes + Wq planes
  ush* qnt_h = (ush*)(R0 + 0);
  ush* qnt_l = (ush*)(R0 + 4194304);
  ush* qni_h = (ush*)(R0 + 8388608);
  ush* qni_l = (ush*)(R0 + 13107200);
  ush* wqt_h = (ush*)(R0 + 17825792);
  ush* wqt_l = (ush*)(R0 + 19922944);
  ush* wqi_h = (ush*)(R0 + 22020096);
  ush* wqi_l = (ush*)(R0 + 24117248);
  // Phase C layout in R0: O hi/lo planes + Wo planes
  ush* ot_h = (ush*)(R0 + 0);
  ush* ot_l = (ush*)(R0 + 4194304);
  ush* oi_h = (ush*)(R0 + 8388608);
  ush* oi_l = (ush*)(R0 + 13107200);
  ush* wo_h = (ush*)(R0 + 17825792);
  ush* wo_l = (ush*)(R0 + 19922944);

  // --- Phase A: K/V path ---
  ln_split<<<2048, 256, 0, stream>>>(k_text, g_t, b_t, knt_h, knt_l);
  ln_split<<<2304, 256, 0, stream>>>(k_image, g_i, b_i, kni_h, kni_l);

  ConvJobs cw;
  cw.j[0] = {Wk_t, wkt_h, wkt_l, 262144};
  cw.j[1] = {Wk_i, wki_h, wki_l, 262144};
  cw.j[2] = {Wv_t, wvt_h, wvt_l, 262144};
  cw.j[3] = {Wv_i, wvi_h, wvi_l, 262144};
  conv_split<<<dim3(1024, 4), 256, 0, stream>>>(cw);

  GemmSJobs kv;
  kv.j[0] = {knt_h, knt_l, wkt_h, wkt_l, bk_t, nullptr, Kbf, 2048, 512, SKV, 0, 1.0f};
  kv.j[1] = {kni_h, kni_l, wki_h, wki_l, bk_i, nullptr, Kbf, 2304, 576, SKV, 512, 1.0f};
  kv.j[2] = {knt_h, knt_l, wvt_h, wvt_l, bv_t, Vc, nullptr, 2048, 512, SKV, 0, 1.0f};
  kv.j[3] = {kni_h, kni_l, wvi_h, wvi_l, bv_i, Vc, nullptr, 2304, 576, SKV, 512, 1.0f};
  gemm_split<<<dim3(8, 18, 4), 256, 0, stream>>>(kv);

  vtrans<<<dim3(17, 64), 256, 0, stream>>>(Vc, Vt);

  // --- Phase B: Q path ---
  ln_split<<<2048, 256, 0, stream>>>(q_text, g_t, b_t, qnt_h, qnt_l);
  ln_split<<<2304, 256, 0, stream>>>(q_image, g_i, b_i, qni_h, qni_l);

  ConvJobs cq;
  cq.j[0] = {Wq_t, wqt_h, wqt_l, 262144};
  cq.j[1] = {Wq_i, wqi_h, wqi_l, 262144};
  cq.j[2] = cq.j[0];
  cq.j[3] = cq.j[0];
  conv_split<<<dim3(1024, 2), 256, 0, stream>>>(cq);

  GemmSJobs qj;
  qj.j[0] = {qnt_h, qnt_l, wqt_h, wqt_l, bq_t, nullptr, Qt_bf, 2048, 512, 512, 0, SCALE};
  qj.j[1] = {qni_h, qni_l, wqi_h, wqi_l, bq_i, nullptr, Qi_bf, 2304, 576, 576, 0, SCALE};
  qj.j[2] = qj.j[0];
  qj.j[3] = qj.j[0];
  gemm_split<<<dim3(8, 18, 2), 256, 0, stream>>>(qj);

  // --- Attention (MFMA flash, single w write, O planes direct) ---
  attn_mfma<<<dim3(18, 64, 2), 256, 0, stream>>>(Qt_bf, Qi_bf, Kbf, Vt,
                                                 w_t, w_i, ot_h, ot_l, oi_h, oi_l);

  // --- Output projection ---
  ConvJobs cwo;
  cwo.j[0] = {Wo, wo_h, wo_l, 262144};
  cwo.j[1] = cwo.j[0];
  cwo.j[2] = cwo.j[0];
  cwo.j[3] = cwo.j[0];
  conv_split<<<dim3(1024, 1), 256, 0, stream>>>(cwo);

  GemmSJobs oj;
  oj.j[0] = {ot_h, ot_l, wo_h, wo_l, bo, out_t, nullptr, 2048, 512, 512, 0, 1.0f};
  oj.j[1] = {oi_h, oi_l, wo_h, wo_l, bo, out_i, nullptr, 2304, 576, 576, 0, 1.0f};
  oj.j[2] = oj.j[0];
  oj.j[3] = oj.j[0];
  gemm_split<<<dim3(8, 18, 2), 256, 0, stream>>>(oj);
}

// Round 4
// 643.783 us; speedup vs baseline: 2.1729x; 1.2035x over previous
//
#include <hip/hip_runtime.h>
#include <math.h>

#define DMODEL 1024
#define SKV 1088
#define SCALE 0.125f

typedef __attribute__((ext_vector_type(8))) short short8;   // 8 bf16 = 4 VGPRs
typedef __attribute__((ext_vector_type(4))) float floatx4;
typedef unsigned short ush;

__device__ __forceinline__ ush bf16_rne(float f) {
  unsigned u = __float_as_uint(f);
  u = (u + 0x7FFFu + ((u >> 16) & 1u)) >> 16;
  return (ush)u;
}
__device__ __forceinline__ float bf16_f32(ush h) {
  return __uint_as_float(((unsigned)h) << 16);
}

#if __has_builtin(__builtin_amdgcn_global_load_lds)
#define HAS_GLL 1
__device__ __forceinline__ void gll16(const ush* g, ush* l) {
  __builtin_amdgcn_global_load_lds(
      (const __attribute__((address_space(1))) unsigned int*)g,
      (__attribute__((address_space(3))) unsigned int*)(unsigned int)(size_t)l,
      16, 0, 0);
}
#else
#define HAS_GLL 0
#endif

// ---------------------------------------------------------------- LayerNorm -> bf16 hi/lo planes
struct LnJob { const float* x; const float* g; const float* b; ush* yh; ush* yl; int rows; };
struct LnJobs { LnJob j[4]; };

__global__ __launch_bounds__(256) void ln_all(LnJobs jobs) {
  LnJob jb = jobs.j[blockIdx.y];
  int row = blockIdx.x;
  if (row >= jb.rows) return;
  const float4* xr = (const float4*)(jb.x + (size_t)row * DMODEL);
  float4 v = xr[threadIdx.x];
  float s = v.x + v.y + v.z + v.w;
  float s2 = v.x * v.x + v.y * v.y + v.z * v.z + v.w * v.w;
  for (int off = 32; off > 0; off >>= 1) {
    s += __shfl_down(s, off, 64);
    s2 += __shfl_down(s2, off, 64);
  }
  __shared__ float ls[4], ls2[4];
  int wid = threadIdx.x >> 6;
  if ((threadIdx.x & 63) == 0) { ls[wid] = s; ls2[wid] = s2; }
  __syncthreads();
  float tot = ls[0] + ls[1] + ls[2] + ls[3];
  float tot2 = ls2[0] + ls2[1] + ls2[2] + ls2[3];
  float mean = tot * (1.0f / DMODEL);
  float var = tot2 * (1.0f / DMODEL) - mean * mean;
  float rstd = rsqrtf(var + 1e-5f);
  float4 gv = ((const float4*)jb.g)[threadIdx.x];
  float4 bv = ((const float4*)jb.b)[threadIdx.x];
  float4 o;
  o.x = (v.x - mean) * rstd * gv.x + bv.x;
  o.y = (v.y - mean) * rstd * gv.y + bv.y;
  o.z = (v.z - mean) * rstd * gv.z + bv.z;
  o.w = (v.w - mean) * rstd * gv.w + bv.w;
  ushort4 hv, lv;
  hv.x = bf16_rne(o.x); lv.x = bf16_rne(o.x - bf16_f32(hv.x));
  hv.y = bf16_rne(o.y); lv.y = bf16_rne(o.y - bf16_f32(hv.y));
  hv.z = bf16_rne(o.z); lv.z = bf16_rne(o.z - bf16_f32(hv.z));
  hv.w = bf16_rne(o.w); lv.w = bf16_rne(o.w - bf16_f32(hv.w));
  ((ushort4*)(jb.yh + (size_t)row * DMODEL))[threadIdx.x] = hv;
  ((ushort4*)(jb.yl + (size_t)row * DMODEL))[threadIdx.x] = lv;
}

// ---------------------------------------------------------------- f32 -> bf16 hi/lo split
struct ConvJob { const float* src; ush* h; ush* l; int n4; };
struct ConvJobs { ConvJob j[6]; };

__global__ __launch_bounds__(256) void conv_split(ConvJobs jobs) {
  ConvJob jb = jobs.j[blockIdx.y];
  int i = blockIdx.x * 256 + threadIdx.x;
  if (i >= jb.n4) return;
  float4 v = ((const float4*)jb.src)[i];
  ushort4 hv, lv;
  hv.x = bf16_rne(v.x); lv.x = bf16_rne(v.x - bf16_f32(hv.x));
  hv.y = bf16_rne(v.y); lv.y = bf16_rne(v.y - bf16_f32(hv.y));
  hv.z = bf16_rne(v.z); lv.z = bf16_rne(v.z - bf16_f32(hv.z));
  hv.w = bf16_rne(v.w); lv.w = bf16_rne(v.w - bf16_f32(hv.w));
  ((ushort4*)jb.h)[i] = hv;
  ((ushort4*)jb.l)[i] = lv;
}

// ---------------------------------------------------------------- split-bf16 MFMA GEMM (NT)
// C = (A @ W^T + bias) * scale with A~Ah+Al, W~Wh+Wl (3 MFMA).
// 128x128 tile, 4 waves (2x2 of 64x64), 16x16x32 bf16, BK=32.
// Staging via global_load_lds width=16; XOR-swizzled chunk slots.
struct GemmSJob {
  const ush *Ah, *Al, *Wh, *Wl;
  const float* bias;
  float* C;    // f32 out (if Cb==null)
  ush* Cb;     // bf16 out (takes priority)
  int M, Sin, Sout, seq_off;
  float scale;
};
struct GemmSJobs { GemmSJob j[6]; };

__device__ __forceinline__ int lds_slot(int m, int kc) {
  return m * 32 + ((kc ^ ((m >> 2) & 3)) << 3);  // ush index, 16B aligned
}

__global__ __launch_bounds__(256) void gemm_split(GemmSJobs jobs) {
  GemmSJob jb = jobs.j[blockIdx.z];
  const int m0 = blockIdx.y * 128;
  if (m0 >= jb.M) return;
  const int n0 = blockIdx.x * 128;

  __shared__ __align__(16) ush sAh[4096];
  __shared__ __align__(16) ush sAl[4096];
  __shared__ __align__(16) ush sWh[4096];
  __shared__ __align__(16) ush sWl[4096];

  const int tid = threadIdx.x;
  const int lane = tid & 63;
  const int wv = tid >> 6;
  const int wm = (wv & 1) * 64;
  const int wn = (wv >> 1) * 64;

  // staging: linear 16B unit L = tid (rows 0..63) and tid+256 (rows 64..127);
  // chunk kc = (L&3) ^ ((row>>2)&3) so LDS dest is exactly base + lane*16.
  const int rowS = tid >> 2;
  const int kcS = (tid & 3) ^ ((rowS >> 2) & 3);
  const size_t aOff0 = (size_t)(m0 + rowS) * DMODEL + kcS * 8;
  const size_t aOff1 = aOff0 + (size_t)64 * DMODEL;
  const size_t wOff0 = (size_t)(n0 + rowS) * DMODEL + kcS * 8;
  const size_t wOff1 = wOff0 + (size_t)64 * DMODEL;
  const int lq0 = tid * 8;          // ush idx, = byte tid*16
  const int lq1 = 2048 + tid * 8;

  const int fr = lane & 15, fc = lane >> 4;
  int offA[4], offB[4];
#pragma unroll
  for (int t = 0; t < 4; ++t) {
    offA[t] = lds_slot(wm + t * 16 + fr, fc);
    offB[t] = lds_slot(wn + t * 16 + fr, fc);
  }

  floatx4 acc[4][4];
#pragma unroll
  for (int mt = 0; mt < 4; ++mt)
#pragma unroll
    for (int nt = 0; nt < 4; ++nt) acc[mt][nt] = (floatx4){0.f, 0.f, 0.f, 0.f};

  for (int k0 = 0; k0 < DMODEL; k0 += 32) {
    __syncthreads();
#if HAS_GLL
    gll16(jb.Ah + aOff0 + k0, sAh + lq0);
    gll16(jb.Ah + aOff1 + k0, sAh + lq1);
    gll16(jb.Al + aOff0 + k0, sAl + lq0);
    gll16(jb.Al + aOff1 + k0, sAl + lq1);
    gll16(jb.Wh + wOff0 + k0, sWh + lq0);
    gll16(jb.Wh + wOff1 + k0, sWh + lq1);
    gll16(jb.Wl + wOff0 + k0, sWl + lq0);
    gll16(jb.Wl + wOff1 + k0, sWl + lq1);
#else
    {
      uint4 a0 = *(const uint4*)(jb.Ah + aOff0 + k0);
      uint4 a1 = *(const uint4*)(jb.Ah + aOff1 + k0);
      uint4 b0 = *(const uint4*)(jb.Al + aOff0 + k0);
      uint4 b1 = *(const uint4*)(jb.Al + aOff1 + k0);
      uint4 c0 = *(const uint4*)(jb.Wh + wOff0 + k0);
      uint4 c1 = *(const uint4*)(jb.Wh + wOff1 + k0);
      uint4 d0 = *(const uint4*)(jb.Wl + wOff0 + k0);
      uint4 d1 = *(const uint4*)(jb.Wl + wOff1 + k0);
      *(uint4*)(sAh + lq0) = a0; *(uint4*)(sAh + lq1) = a1;
      *(uint4*)(sAl + lq0) = b0; *(uint4*)(sAl + lq1) = b1;
      *(uint4*)(sWh + lq0) = c0; *(uint4*)(sWh + lq1) = c1;
      *(uint4*)(sWl + lq0) = d0; *(uint4*)(sWl + lq1) = d1;
    }
#endif
    __syncthreads();
    short8 ah[4], al[4];
#pragma unroll
    for (int t = 0; t < 4; ++t) {
      ah[t] = *(const short8*)(sAh + offA[t]);
      al[t] = *(const short8*)(sAl + offA[t]);
    }
#pragma unroll
    for (int nt = 0; nt < 4; ++nt) {
      short8 bh = *(const short8*)(sWh + offB[nt]);
      short8 bl = *(const short8*)(sWl + offB[nt]);
#pragma unroll
      for (int mt = 0; mt < 4; ++mt) {
        acc[mt][nt] = __builtin_amdgcn_mfma_f32_16x16x32_bf16(ah[mt], bh, acc[mt][nt], 0, 0, 0);
        acc[mt][nt] = __builtin_amdgcn_mfma_f32_16x16x32_bf16(ah[mt], bl, acc[mt][nt], 0, 0, 0);
        acc[mt][nt] = __builtin_amdgcn_mfma_f32_16x16x32_bf16(al[mt], bh, acc[mt][nt], 0, 0, 0);
      }
    }
  }

  float bias_v[4];
#pragma unroll
  for (int nt = 0; nt < 4; ++nt) bias_v[nt] = jb.bias[n0 + wn + nt * 16 + fr];
  if (jb.Cb) {
#pragma unroll
    for (int mt = 0; mt < 4; ++mt) {
#pragma unroll
      for (int r = 0; r < 4; ++r) {
        int rowA = m0 + wm + mt * 16 + fc * 4 + r;
        int rowOut = (rowA / jb.Sin) * jb.Sout + jb.seq_off + (rowA % jb.Sin);
        ush* crow = jb.Cb + (size_t)rowOut * DMODEL + n0 + wn + fr;
#pragma unroll
        for (int nt = 0; nt < 4; ++nt)
          crow[nt * 16] = bf16_rne((acc[mt][nt][r] + bias_v[nt]) * jb.scale);
      }
    }
  } else {
#pragma unroll
    for (int mt = 0; mt < 4; ++mt) {
#pragma unroll
      for (int r = 0; r < 4; ++r) {
        int rowA = m0 + wm + mt * 16 + fc * 4 + r;
        int rowOut = (rowA / jb.Sin) * jb.Sout + jb.seq_off + (rowA % jb.Sin);
        float* crow = jb.C + (size_t)rowOut * DMODEL + n0 + wn + fr;
#pragma unroll
        for (int nt = 0; nt < 4; ++nt)
          crow[nt * 16] = (acc[mt][nt][r] + bias_v[nt]) * jb.scale;
      }
    }
  }
}

// ---------------------------------------------------------------- V transpose: bf16 [b][kv][h*64+d] -> bf16 [bh][d][kv]
__global__ __launch_bounds__(256) void vtrans(const ush* __restrict__ Vbf, ush* __restrict__ Vt) {
  int k0 = blockIdx.x * 64;
  int bh = blockIdx.y;
  int b = bh >> 4, h = bh & 15;
  __shared__ ush T[64][72];
  int t = threadIdx.x;
  int c4 = (t & 15) * 4;
  int r = t >> 4;
#pragma unroll
  for (int i = 0; i < 4; ++i) {
    int kr = r + i * 16;
    ushort4 v = *(const ushort4*)(Vbf + (size_t)(b * SKV + k0 + kr) * DMODEL + h * 64 + c4);
    T[c4 + 0][kr] = v.x;
    T[c4 + 1][kr] = v.y;
    T[c4 + 2][kr] = v.z;
    T[c4 + 3][kr] = v.w;
  }
  __syncthreads();
#pragma unroll
  for (int i = 0; i < 4; ++i) {
    int dr = r + i * 16;
    ushort4 o;
    o.x = T[dr][c4 + 0]; o.y = T[dr][c4 + 1]; o.z = T[dr][c4 + 2]; o.w = T[dr][c4 + 3];
    *(ushort4*)(Vt + ((size_t)bh * 64 + dr) * SKV + k0 + c4) = o;
  }
}

// ---------------------------------------------------------------- MFMA flash attention, LDS-staged tiles
// Block = (64 q-rows, bh, mod), 4 waves each owning 16 q-rows (all k).
// Sweep 1: stage K tile, online (m,l) per wave (butterfly over fr only).
// Sweep 2: stage K+V tiles, recompute, write w once, P->LDS->A-frag, O += P.V^T.
__global__ __launch_bounds__(256) void attn_mfma(
    const ush* __restrict__ Qtb, const ush* __restrict__ Qib,
    const ush* __restrict__ Kbf, const ush* __restrict__ Vtp,
    float* __restrict__ Wt, float* __restrict__ Wi,
    ush* __restrict__ OtH, ush* __restrict__ OtL,
    ush* __restrict__ OiH, ush* __restrict__ OiL) {
  const int mod = blockIdx.z;
  const int Sq = mod ? 576 : 512;
  const int q0 = blockIdx.x * 64;
  if (q0 >= Sq) return;
  const int bh = blockIdx.y;
  const int b = bh >> 4, h = bh & 15;
  const ush* Q = mod ? Qib : Qtb;
  float* Wout = mod ? Wi : Wt;
  ush* OH = mod ? OiH : OtH;
  ush* OL = mod ? OiL : OtL;

  __shared__ __align__(16) ush sK[64 * 64];
  __shared__ __align__(16) ush sV[64 * 64];
  __shared__ __align__(16) ush sP[4][16 * 64];

  const int tid = threadIdx.x;
  const int lane = tid & 63;
  const int wv = tid >> 6;
  const int fr = lane & 15;
  const int fc = lane >> 4;

  // cooperative staging: thread t covers row t>>2, chunks 2(t&3), 2(t&3)+1 (32B)
  const int srow = tid >> 2;
  const int sch = (tid & 3) * 2;
  const int ssl = sch ^ (srow & 7);
  ush* skw0 = sK + srow * 64 + ssl * 8;
  ush* skw1 = sK + srow * 64 + (ssl ^ 1) * 8;
  ush* svw0 = sV + srow * 64 + ssl * 8;
  ush* svw1 = sV + srow * 64 + (ssl ^ 1) * 8;
  const ush* Kg = Kbf + (size_t)(b * SKV + srow) * DMODEL + h * 64 + sch * 8;
  const ush* Vg = Vtp + ((size_t)bh * 64 + srow) * SKV + sch * 8;

  // persistent Q A-fragments (d 0..31 / 32..63)
  const ush* qrow = Q + (size_t)(b * Sq + q0 + wv * 16 + fr) * DMODEL + h * 64 + fc * 8;
  short8 qa0 = *(const short8*)qrow;
  short8 qa1 = *(const short8*)(qrow + 32);

  // fragment read offsets (ush idx), slot = chunk ^ (row&7)
  const int sw = fr & 7;
  int kOffL[4], kOffH[4];
#pragma unroll
  for (int j = 0; j < 4; ++j) {
    int base = (j * 16 + fr) * 64;
    kOffL[j] = base + (fc ^ sw) * 8;
    kOffH[j] = base + ((fc + 4) ^ sw) * 8;
  }
  const int pOffL = fr * 64 + (fc ^ sw) * 8;
  const int pOffH = fr * 64 + ((fc + 4) ^ sw) * 8;

  float m[4], l[4];
#pragma unroll
  for (int r = 0; r < 4; ++r) { m[r] = -3e38f; l[r] = 0.f; }

  // ---- Sweep 1: stats ----
  for (int kt = 0; kt < 17; ++kt) {
    __syncthreads();
    {
      const ush* kp = Kg + (size_t)(kt * 64) * DMODEL;
      uint4 x = *(const uint4*)kp;
      uint4 y = *(const uint4*)(kp + 8);
      *(uint4*)skw0 = x;
      *(uint4*)skw1 = y;
    }
    __syncthreads();
    floatx4 s[4];
#pragma unroll
    for (int j = 0; j < 4; ++j) {
      short8 b0 = *(const short8*)(sK + kOffL[j]);
      short8 b1 = *(const short8*)(sK + kOffH[j]);
      floatx4 z = (floatx4){0.f, 0.f, 0.f, 0.f};
      z = __builtin_amdgcn_mfma_f32_16x16x32_bf16(qa0, b0, z, 0, 0, 0);
      s[j] = __builtin_amdgcn_mfma_f32_16x16x32_bf16(qa1, b1, z, 0, 0, 0);
    }
#pragma unroll
    for (int r = 0; r < 4; ++r) {
      float mx = fmaxf(fmaxf(s[0][r], s[1][r]), fmaxf(s[2][r], s[3][r]));
      float mn = fmaxf(m[r], mx);
      l[r] = l[r] * __expf(m[r] - mn) + __expf(s[0][r] - mn) + __expf(s[1][r] - mn) +
             __expf(s[2][r] - mn) + __expf(s[3][r] - mn);
      m[r] = mn;
    }
  }
  // butterfly merge across fr (k-columns); wave fully owns its q-rows
#pragma unroll
  for (int off = 1; off <= 8; off <<= 1) {
#pragma unroll
    for (int r = 0; r < 4; ++r) {
      float mo = __shfl_xor(m[r], off, 64);
      float lo = __shfl_xor(l[r], off, 64);
      float mn = fmaxf(m[r], mo);
      l[r] = l[r] * __expf(m[r] - mn) + lo * __expf(mo - mn);
      m[r] = mn;
    }
  }
  float rl[4];
#pragma unroll
  for (int r = 0; r < 4; ++r) rl[r] = 1.0f / l[r];

  floatx4 oacc[4];
#pragma unroll
  for (int j = 0; j < 4; ++j) oacc[j] = (floatx4){0.f, 0.f, 0.f, 0.f};

  float* wbase = Wout + ((size_t)bh * Sq + q0 + wv * 16) * SKV;

  // ---- Sweep 2: recompute, normalize, write w, PV ----
  for (int kt = 0; kt < 17; ++kt) {
    const int k0 = kt * 64;
    __syncthreads();
    {
      const ush* kp = Kg + (size_t)k0 * DMODEL;
      uint4 x = *(const uint4*)kp;
      uint4 y = *(const uint4*)(kp + 8);
      const ush* vp = Vg + k0;
      uint4 vx = *(const uint4*)vp;
      uint4 vy = *(const uint4*)(vp + 8);
      *(uint4*)skw0 = x;
      *(uint4*)skw1 = y;
      *(uint4*)svw0 = vx;
      *(uint4*)svw1 = vy;
    }
    __syncthreads();
    floatx4 s[4];
#pragma unroll
    for (int j = 0; j < 4; ++j) {
      short8 b0 = *(const short8*)(sK + kOffL[j]);
      short8 b1 = *(const short8*)(sK + kOffH[j]);
      floatx4 z = (floatx4){0.f, 0.f, 0.f, 0.f};
      z = __builtin_amdgcn_mfma_f32_16x16x32_bf16(qa0, b0, z, 0, 0, 0);
      s[j] = __builtin_amdgcn_mfma_f32_16x16x32_bf16(qa1, b1, s[j] = z, 0, 0, 0);
    }
#pragma unroll
    for (int j = 0; j < 4; ++j) {
#pragma unroll
      for (int r = 0; r < 4; ++r) {
        float w = __expf(s[j][r] - m[r]) * rl[r];
        wbase[(size_t)(fc * 4 + r) * SKV + k0 + j * 16 + fr] = w;
        int row = fc * 4 + r;
        int chunk = j * 2 + (fr >> 3);
        sP[wv][row * 64 + ((chunk ^ (row & 7)) * 8) + (fr & 7)] = bf16_rne(w);
      }
    }
    short8 pa0 = *(const short8*)(sP[wv] + pOffL);
    short8 pa1 = *(const short8*)(sP[wv] + pOffH);
#pragma unroll
    for (int j = 0; j < 4; ++j) {
      short8 v0 = *(const short8*)(sV + kOffL[j]);
      short8 v1 = *(const short8*)(sV + kOffH[j]);
      oacc[j] = __builtin_amdgcn_mfma_f32_16x16x32_bf16(pa0, v0, oacc[j], 0, 0, 0);
      oacc[j] = __builtin_amdgcn_mfma_f32_16x16x32_bf16(pa1, v1, oacc[j], 0, 0, 0);
    }
  }

  // ---- O epilogue: hi/lo bf16 planes ----
#pragma unroll
  for (int j = 0; j < 4; ++j) {
#pragma unroll
    for (int r = 0; r < 4; ++r) {
      int q = q0 + wv * 16 + fc * 4 + r;
      size_t oidx = (size_t)(b * Sq + q) * DMODEL + h * 64 + j * 16 + fr;
      float o = oacc[j][r];
      ush hh = bf16_rne(o);
      OH[oidx] = hh;
      OL[oidx] = bf16_rne(o - bf16_f32(hh));
    }
  }
}

// ---------------------------------------------------------------- launch
extern "C" void kernel_launch(void* const* d_in, const int* in_sizes, int n_in,
                              void* d_out, int out_size, void* d_ws, size_t ws_size,
                              hipStream_t stream) {
  const float* q_text = (const float*)d_in[0];
  const float* q_image = (const float*)d_in[1];
  const float* k_text = (const float*)d_in[2];
  const float* k_image = (const float*)d_in[3];
  const float* Wq_t = (const float*)d_in[4];
  const float* bq_t = (const float*)d_in[5];
  const float* Wk_t = (const float*)d_in[6];
  const float* bk_t = (const float*)d_in[7];
  const float* Wv_t = (const float*)d_in[8];
  const float* bv_t = (const float*)d_in[9];
  const float* Wq_i = (const float*)d_in[10];
  const float* bq_i = (const float*)d_in[11];
  const float* Wk_i = (const float*)d_in[12];
  const float* bk_i = (const float*)d_in[13];
  const float* Wv_i = (const float*)d_in[14];
  const float* bv_i = (const float*)d_in[15];
  const float* g_t = (const float*)d_in[16];
  const float* b_t = (const float*)d_in[17];
  const float* g_i = (const float*)d_in[18];
  const float* b_i = (const float*)d_in[19];
  const float* Wo = (const float*)d_in[20];
  const float* bo = (const float*)d_in[21];

  float* out = (float*)d_out;
  float* out_t = out;
  float* out_i = out + 2097152;
  float* w_t = out + 4456448;
  float* w_i = out + 40108032;

  char* W = (char*)d_ws;
  ush* Kbf = (ush*)(W + 0);                  // 8,912,896
  ush* Vbf = (ush*)(W + 8912896);            // 8,912,896
  ush* Qt_bf = (ush*)(W + 17825792);         // 4,194,304
  ush* Qi_bf = (ush*)(W + 22020096);         // 4,718,592
  ush* knt_h = (ush*)(W + 26738688);         // 4,194,304
  ush* knt_l = (ush*)(W + 30932992);         // 4,194,304
  ush* kni_h = (ush*)(W + 35127296);         // 4,718,592
  ush* kni_l = (ush*)(W + 39845888);         // 4,718,592
  ush* qnt_h = (ush*)(W + 44564480);         // 4,194,304
  ush* qnt_l = (ush*)(W + 48758784);         // 4,194,304
  ush* qni_h = (ush*)(W + 52953088);         // 4,718,592
  ush* qni_l = (ush*)(W + 57671680);         // 4,718,592 (ends 62,390,272)
  ush* wkt_h = (ush*)(W + 62390272);
  ush* wkt_l = (ush*)(W + 64487424);
  ush* wki_h = (ush*)(W + 66584576);
  ush* wki_l = (ush*)(W + 68681728);
  ush* wvt_h = (ush*)(W + 70778880);
  ush* wvt_l = (ush*)(W + 72876032);
  ush* wvi_h = (ush*)(W + 74973184);
  ush* wvi_l = (ush*)(W + 77070336);
  ush* wqt_h = (ush*)(W + 79167488);
  ush* wqt_l = (ush*)(W + 81264640);
  ush* wqi_h = (ush*)(W + 83361792);
  ush* wqi_l = (ush*)(W + 85458944);         // ends 87,556,096
  // after gemm3: qn region is dead -> reuse for Vt + wo planes
  ush* Vt = (ush*)(W + 44564480);            // 8,912,896 (ends 53,477,376)
  ush* wo_h = (ush*)(W + 53477376);          // 2,097,152
  ush* wo_l = (ush*)(W + 55574528);          // 2,097,152
  // after gemm3: kn region is dead -> O planes
  ush* ot_h = knt_h;
  ush* ot_l = knt_l;
  ush* oi_h = kni_h;
  ush* oi_l = kni_l;

  // --- LN (all 4 tensors) ---
  LnJobs lj;
  lj.j[0] = {k_text, g_t, b_t, knt_h, knt_l, 2048};
  lj.j[1] = {k_image, g_i, b_i, kni_h, kni_l, 2304};
  lj.j[2] = {q_text, g_t, b_t, qnt_h, qnt_l, 2048};
  lj.j[3] = {q_image, g_i, b_i, qni_h, qni_l, 2304};
  ln_all<<<dim3(2304, 4), 256, 0, stream>>>(lj);

  // --- weight splits (K,V,Q) ---
  ConvJobs cw;
  cw.j[0] = {Wk_t, wkt_h, wkt_l, 262144};
  cw.j[1] = {Wk_i, wki_h, wki_l, 262144};
  cw.j[2] = {Wv_t, wvt_h, wvt_l, 262144};
  cw.j[3] = {Wv_i, wvi_h, wvi_l, 262144};
  cw.j[4] = {Wq_t, wqt_h, wqt_l, 262144};
  cw.j[5] = {Wq_i, wqi_h, wqi_l, 262144};
  conv_split<<<dim3(1024, 6), 256, 0, stream>>>(cw);

  // --- all projections in one dispatch ---
  GemmSJobs pj;
  pj.j[0] = {knt_h, knt_l, wkt_h, wkt_l, bk_t, nullptr, Kbf, 2048, 512, SKV, 0, 1.0f};
  pj.j[1] = {kni_h, kni_l, wki_h, wki_l, bk_i, nullptr, Kbf, 2304, 576, SKV, 512, 1.0f};
  pj.j[2] = {knt_h, knt_l, wvt_h, wvt_l, bv_t, nullptr, Vbf, 2048, 512, SKV, 0, 1.0f};
  pj.j[3] = {kni_h, kni_l, wvi_h, wvi_l, bv_i, nullptr, Vbf, 2304, 576, SKV, 512, 1.0f};
  pj.j[4] = {qnt_h, qnt_l, wqt_h, wqt_l, bq_t, nullptr, Qt_bf, 2048, 512, 512, 0, SCALE};
  pj.j[5] = {qni_h, qni_l, wqi_h, wqi_l, bq_i, nullptr, Qi_bf, 2304, 576, 576, 0, SCALE};
  gemm_split<<<dim3(8, 18, 6), 256, 0, stream>>>(pj);

  // --- V transpose (qn region now dead) ---
  vtrans<<<dim3(17, 64), 256, 0, stream>>>(Vbf, Vt);

  // --- Wo split (into dead qn region) ---
  ConvJobs cwo;
  cwo.j[0] = {Wo, wo_h, wo_l, 262144};
  cwo.j[1] = cwo.j[0]; cwo.j[2] = cwo.j[0];
  cwo.j[3] = cwo.j[0]; cwo.j[4] = cwo.j[0]; cwo.j[5] = cwo.j[0];
  conv_split<<<dim3(1024, 1), 256, 0, stream>>>(cwo);

  // --- attention ---
  attn_mfma<<<dim3(9, 64, 2), 256, 0, stream>>>(Qt_bf, Qi_bf, Kbf, Vt,
                                                w_t, w_i, ot_h, ot_l, oi_h, oi_l);

  // --- output projection ---
  GemmSJobs oj;
  oj.j[0] = {ot_h, ot_l, wo_h, wo_l, bo, out_t, nullptr, 2048, 512, 512, 0, 1.0f};
  oj.j[1] = {oi_h, oi_l, wo_h, wo_l, bo, out_i, nullptr, 2304, 576, 576, 0, 1.0f};
  oj.j[2] = oj.j[0]; oj.j[3] = oj.j[0]; oj.j[4] = oj.j[0]; oj.j[5] = oj.j[0];
  gemm_split<<<dim3(8, 18, 2), 256, 0, stream>>>(oj);
}